// Round 11
// baseline (167.853 us; speedup 1.0000x reference)
//
#include <hip/hip_runtime.h>
#include <hip/hip_bf16.h>

using bf16 = __hip_bfloat16;
typedef __attribute__((ext_vector_type(8))) short bf16x8;
typedef __attribute__((ext_vector_type(4))) short bf16x4;
typedef __attribute__((ext_vector_type(4))) float f32x4;
typedef __attribute__((ext_vector_type(16))) float f32x16;

static constexpr int Bb = 4, Ss = 2048, Dd = 1024, Hh = 16, HD = 64;
static constexpr int TD = 3 * Dd;            // 3072
static constexpr int Mrows = Bb * Ss;        // 8192

#define MFMA16(a, b, c) __builtin_amdgcn_mfma_f32_16x16x32_bf16((a), (b), (c), 0, 0, 0)
#define MFMA32(a, b, c) __builtin_amdgcn_mfma_f32_32x32x16_bf16((a), (b), (c), 0, 0, 0)

__device__ __forceinline__ void gload_lds16(const void* g, void* l) {
    __builtin_amdgcn_global_load_lds(
        (const __attribute__((address_space(1))) void*)g,
        (__attribute__((address_space(3))) void*)l, 16, 0, 0);
}

__device__ __forceinline__ unsigned lds_addr(const void* p) {
    return (unsigned)(unsigned long long)(const __attribute__((address_space(3))) char*)p;
}

__device__ __forceinline__ unsigned pack2bf(float a, float b) {
    bf16 x = __float2bfloat16(a), y = __float2bfloat16(b);
    return (unsigned)(*(unsigned short*)&x) | ((unsigned)(*(unsigned short*)&y) << 16);
}

// ---------------- fused cast fp32 -> bf16 (x, Wqkv, Wo in one launch) ------
__global__ void cast_all(const float* __restrict__ x, const float* __restrict__ w1,
                         const float* __restrict__ w2, bf16* __restrict__ xb,
                         bf16* __restrict__ w1b, bf16* __restrict__ w2b) {
    int i = blockIdx.x * blockDim.x + threadIdx.x;   // 4-elem groups
    const float* src; bf16* dst; int off;
    if (i < 2097152)      { src = x;  dst = xb;  off = i; }
    else if (i < 2883584) { src = w1; dst = w1b; off = i - 2097152; }
    else                  { src = w2; dst = w2b; off = i - 2883584; }
    float4 v = ((const float4*)src)[off];
    uint2 o;
    o.x = pack2bf(v.x, v.y);
    o.y = pack2bf(v.z, v.w);
    *(uint2*)(dst + 4l * off) = o;
}

// ---------------- GEMM 256x128, BK=64, 8 waves, counted-vmcnt pipeline -----
// v11 = r10 geometry with m201's T4 staging discipline (the ONE change):
// K-tiles processed in pairs (buf = kt&1). All 6 loads for kt+2 are issued
// immediately after buf's last-read barrier (end of its P3); the matching
// s_waitcnt vmcnt(6) comes ONE FULL K-TILE LATER (4 phases, ~1600cy slack)
// with exactly 12 outstanding -> waits only the older 6 (landed long ago).
// Never vmcnt(0) in-loop. Phases: {ds_reads(8/4/4/0); s_barrier; lgkm(auto);
// setprio(1); 8 MFMA; setprio(0); s_barrier}. T2 XOR-swizzle (conflicts=0).
template<bool OUT_BF16>
__global__ __launch_bounds__(512, 1) void gemm256x128(
    const bf16* __restrict__ A, const bf16* __restrict__ Bt,
    bf16* __restrict__ Cb, float* __restrict__ Cf, const float* __restrict__ bias,
    int M, int N, int K)
{
    __shared__ __align__(16) bf16 As[2][256 * 64];   // 64 KB
    __shared__ __align__(16) bf16 Bs[2][128 * 64];   // 32 KB
    const int tid = threadIdx.x;
    const int lane = tid & 63;
    const int wid = tid >> 6;
    const int lc = lane & 15, lg = lane >> 4;
    const int wm = wid >> 1, wn = wid & 1;           // 4x2 wave grid, 64x64/wave

    const int gx = N >> 7;                           // tiles along N (128)
    const int nwg = gridDim.x;
    int orig = blockIdx.x;
    int swz = ((nwg & 7) == 0) ? ((orig & 7) * (nwg >> 3) + (orig >> 3)) : orig;
    const long tile_m = (long)(swz / gx) * 256;
    const long tile_n = (long)(swz % gx) * 128;

    // stage one full K-tile (A 256x64 + B 128x64) = 6 gload_lds16/thread.
    // LDS linear in slot s; global col-seg pre-swizzled (G21 involution).
    auto STAGE6 = [&](int buf, int kt) {
#pragma unroll
        for (int i = 0; i < 4; ++i) {
            int s = tid + i * 512;
            int r = s >> 3;
            int cs = (s & 7) ^ (r & 7);
            gload_lds16(A + (tile_m + r) * (long)K + kt * 64 + cs * 8,
                        (char*)As[buf] + s * 16);
        }
#pragma unroll
        for (int i = 0; i < 2; ++i) {
            int s = tid + i * 512;
            int r = s >> 3;
            int cs = (s & 7) ^ (r & 7);
            gload_lds16(Bt + (tile_n + r) * (long)K + kt * 64 + cs * 8,
                        (char*)Bs[buf] + s * 16);
        }
    };
    auto LDA = [&](int buf, int mi, int ks) -> bf16x8 {
        int row = wm * 64 + mi * 16 + lc;
        int byte = (row * 128 + ks * 64 + lg * 16) ^ ((row & 7) << 4);
        return *(const bf16x8*)((const char*)As[buf] + byte);
    };
    auto LDB = [&](int buf, int nj, int ks) -> bf16x8 {
        int row = wn * 64 + nj * 16 + lc;
        int byte = (row * 128 + ks * 64 + lg * 16) ^ ((row & 7) << 4);
        return *(const bf16x8*)((const char*)Bs[buf] + byte);
    };

    const f32x4 fz = {0.f, 0.f, 0.f, 0.f};
    f32x4 acc[4][4];
#pragma unroll
    for (int i = 0; i < 4; ++i)
#pragma unroll
        for (int j = 0; j < 4; ++j) acc[i][j] = fz;

    const int nkt = K >> 6;                          // 16 (even)

#define BAR() asm volatile("s_barrier" ::: "memory")

    // 4 compute phases on one buffer (reads 8/4/4/0, 8 MFMA each)
    auto PHASES = [&](int b) {
        bf16x8 a0[2][2], a1[2][2], b0[2][2], b1[2][2];
        // P0: a(mi0-1), b(nj0-1); Q00
#pragma unroll
        for (int mi = 0; mi < 2; ++mi) { a0[mi][0] = LDA(b, mi, 0); a0[mi][1] = LDA(b, mi, 1); }
#pragma unroll
        for (int nj = 0; nj < 2; ++nj) { b0[nj][0] = LDB(b, nj, 0); b0[nj][1] = LDB(b, nj, 1); }
        BAR();
        __builtin_amdgcn_s_setprio(1);
#pragma unroll
        for (int mi = 0; mi < 2; ++mi)
#pragma unroll
            for (int nj = 0; nj < 2; ++nj)
#pragma unroll
                for (int ks = 0; ks < 2; ++ks)
                    acc[mi][nj] = MFMA16(a0[mi][ks], b0[nj][ks], acc[mi][nj]);
        __builtin_amdgcn_s_setprio(0);
        BAR();
        // P1: b(nj2-3); Q01
#pragma unroll
        for (int nj = 0; nj < 2; ++nj) { b1[nj][0] = LDB(b, nj + 2, 0); b1[nj][1] = LDB(b, nj + 2, 1); }
        BAR();
        __builtin_amdgcn_s_setprio(1);
#pragma unroll
        for (int mi = 0; mi < 2; ++mi)
#pragma unroll
            for (int nj = 0; nj < 2; ++nj)
#pragma unroll
                for (int ks = 0; ks < 2; ++ks)
                    acc[mi][nj + 2] = MFMA16(a0[mi][ks], b1[nj][ks], acc[mi][nj + 2]);
        __builtin_amdgcn_s_setprio(0);
        BAR();
        // P2: a(mi2-3); Q11
#pragma unroll
        for (int mi = 0; mi < 2; ++mi) { a1[mi][0] = LDA(b, mi + 2, 0); a1[mi][1] = LDA(b, mi + 2, 1); }
        BAR();
        __builtin_amdgcn_s_setprio(1);
#pragma unroll
        for (int mi = 0; mi < 2; ++mi)
#pragma unroll
            for (int nj = 0; nj < 2; ++nj)
#pragma unroll
                for (int ks = 0; ks < 2; ++ks)
                    acc[mi + 2][nj + 2] = MFMA16(a1[mi][ks], b1[nj][ks], acc[mi + 2][nj + 2]);
        __builtin_amdgcn_s_setprio(0);
        BAR();
        // P3: no reads; Q10 (regs only). Trailing BAR = buffer free.
        __builtin_amdgcn_s_setprio(1);
#pragma unroll
        for (int mi = 0; mi < 2; ++mi)
#pragma unroll
            for (int nj = 0; nj < 2; ++nj)
#pragma unroll
                for (int ks = 0; ks < 2; ++ks)
                    acc[mi + 2][nj] = MFMA16(a1[mi][ks], b0[nj][ks], acc[mi + 2][nj]);
        __builtin_amdgcn_s_setprio(0);
        BAR();
    };

    // prologue: kt0 -> buf0, kt1 -> buf1 (12 outstanding); wait older 6
    STAGE6(0, 0);
    STAGE6(1, 1);
    asm volatile("s_waitcnt vmcnt(6)" ::: "memory");
    BAR();

    for (int t = 0; t < nkt / 2; ++t) {
        const int kt0 = 2 * t, kt1 = 2 * t + 1;
        // ---- K-tile kt0 on buf0 (data waited) ----
        PHASES(0);
        {   // buf0's reads all done (P3 trailing BAR): refill with kt0+2
            int sk = kt0 + 2 < nkt ? kt0 + 2 : nkt - 1;   // tail: dead re-stage
            STAGE6(0, sk);
        }
        // outstanding = kt1's 6 + kt0+2's 6 = 12; wait kt1's (issued 4+ phases ago)
        asm volatile("s_waitcnt vmcnt(6)" ::: "memory");
        BAR();
        // ---- K-tile kt1 on buf1 ----
        PHASES(1);
        {
            int sk = kt1 + 2 < nkt ? kt1 + 2 : nkt - 1;
            STAGE6(1, sk);
        }
        // outstanding = kt0+2's 6 + kt1+2's 6 = 12; wait kt0+2's
        asm volatile("s_waitcnt vmcnt(6)" ::: "memory");
        BAR();
    }
    asm volatile("s_waitcnt vmcnt(0)" ::: "memory");   // DMA must not outlive block

#undef BAR

    // ---- epilogue: C/D layout row=lg*4+rr, col=lc ----
#pragma unroll
    for (int mi = 0; mi < 4; ++mi)
#pragma unroll
        for (int nj = 0; nj < 4; ++nj)
#pragma unroll
            for (int rr = 0; rr < 4; ++rr) {
                long row = tile_m + wm * 64 + mi * 16 + lg * 4 + rr;
                long col = tile_n + wn * 64 + nj * 16 + lc;
                float v = acc[mi][nj][rr];
                if constexpr (OUT_BF16) Cb[row * N + col] = __float2bfloat16(v);
                else                    Cf[row * N + col] = v + bias[col];
            }
}

// ---------------- causal flash attention v6: single strip, heavy-first ----
__global__ __launch_bounds__(256, 2) void attn_fwd6(const bf16* __restrict__ qkv,
                                                    bf16* __restrict__ out) {
    const int bh = blockIdx.x;                 // 0..63
    const int p  = blockIdx.y;                 // 0..15
    const int s  = 15 - p;                     // strip index, heavy first
    const int b = bh >> 4, h = bh & 15;
    const int tid = threadIdx.x;
    const int lane = tid & 63, wid = tid >> 6;
    const int ln31 = lane & 31, hi = lane >> 5;
    const int ch = (lane >> 4) & 1, c16 = lane & 15;
    const long rowbase = (long)b * Ss;
    const int q0 = s * 128 + wid * 32;         // this wave's 32 q-rows
    const int nt = 2 * s + 2;                  // causal kv tiles
    const float CL2 = 0.18033688f;             // 0.125 * log2(e)

    __shared__ __align__(16) bf16 Ks[2][64 * 64];
    __shared__ __align__(16) bf16 Vs[2][64 * 64];

    const int sK0 = tid, sK1 = tid + 256;
    const int rK0 = sK0 >> 3, cK0 = ((sK0 & 7) ^ (rK0 & 7)) * 8;
    const int rK1 = sK1 >> 3, cK1 = ((sK1 & 7) ^ (rK1 & 7)) * 8;
    const int rV0 = ((sK0 >> 5) << 2) | ((sK0 >> 1) & 3);
    const int cV0 = ((((sK0 >> 3) & 3) << 1) | (sK0 & 1)) * 8;
    const int rV1 = ((sK1 >> 5) << 2) | ((sK1 >> 1) & 3);
    const int cV1 = ((((sK1 >> 3) & 3) << 1) | (sK1 & 1)) * 8;
    const bf16* gK0 = qkv + (rowbase + rK0) * (long)TD + h * HD + Dd + cK0;
    const bf16* gK1 = qkv + (rowbase + rK1) * (long)TD + h * HD + Dd + cK1;
    const bf16* gV0 = qkv + (rowbase + rV0) * (long)TD + h * HD + 2 * Dd + cV0;
    const bf16* gV1 = qkv + (rowbase + rV1) * (long)TD + h * HD + 2 * Dd + cV1;

    auto STAGE = [&](int buf, int kt) {
        const long o = (long)kt * 64 * TD;
        gload_lds16(gK0 + o, (char*)Ks[buf] + tid * 16);
        gload_lds16(gK1 + o, (char*)Ks[buf] + 4096 + tid * 16);
        gload_lds16(gV0 + o, (char*)Vs[buf] + tid * 16);
        gload_lds16(gV1 + o, (char*)Vs[buf] + 4096 + tid * 16);
    };

    bf16x8 qa[4];
#pragma unroll
    for (int dk = 0; dk < 4; ++dk)
        qa[dk] = *(const bf16x8*)(qkv + (rowbase + q0 + ln31) * (long)TD + h * HD + dk * 16 + hi * 8);

    f32x16 acc[2];
#pragma unroll
    for (int dt = 0; dt < 2; ++dt) acc[dt] = (f32x16)0.0f;
    float m2 = -3.0e38f;
    float l = 0.f;

    STAGE(0, 0);
    __syncthreads();

    for (int kt = 0; kt < nt; ++kt) {
        const int cur = kt & 1;
        if (kt + 1 < nt) STAGE(cur ^ 1, kt + 1);

        if (kt * 64 <= q0 + 31) {
            const char* kbp = (const char*)Ks[cur];
            const char* vbp = (const char*)Vs[cur];
            f32x16 sc[2];
            __builtin_amdgcn_s_setprio(1);
#pragma unroll
            for (int st = 0; st < 2; ++st) {
                f32x16 z = (f32x16)0.0f;
                const int row = st * 32 + ln31;
                const int sw = (row & 7) << 4;
#pragma unroll
                for (int dk = 0; dk < 4; ++dk) {
                    bf16x8 ka = *(const bf16x8*)(kbp + ((row * 128 + dk * 32 + hi * 16) ^ sw));
                    z = MFMA32(ka, qa[dk], z);
                }
                sc[st] = z;
            }
            __builtin_amdgcn_s_setprio(0);
            if (kt * 64 + 63 > q0) {
                const int qg = q0 + ln31;
                const int kbase = kt * 64 + 4 * hi;
#pragma unroll
                for (int st = 0; st < 2; ++st)
#pragma unroll
                    for (int r = 0; r < 16; ++r) {
                        int kg = kbase + st * 32 + (r & 3) + 8 * (r >> 2);
                        if (kg > qg) sc[st][r] = -3.0e38f;
                    }
            }
            float mx = sc[0][0];
#pragma unroll
            for (int r = 1; r < 16; ++r) mx = fmaxf(mx, sc[0][r]);
#pragma unroll
            for (int r = 0; r < 16; ++r) mx = fmaxf(mx, sc[1][r]);
            mx = fmaxf(mx, __shfl_xor(mx, 32));
            float pmax2 = mx * CL2;
            if (__ballot(pmax2 > m2 + 8.0f)) {
                float mnew = fmaxf(m2, pmax2);
                float sf = __builtin_amdgcn_exp2f(m2 - mnew);
                m2 = mnew;
                l *= sf;
#pragma unroll
                for (int r = 0; r < 16; ++r) {
                    float sfr = __shfl(sf, (r & 3) + 8 * (r >> 2) + 4 * hi);
                    acc[0][r] *= sfr;
                    acc[1][r] *= sfr;
                }
            }
            bf16x4 vl[4][2], vh[4][2];
            const unsigned vbase = lds_addr(vbp) + hi * 1024 + ch * 128 + c16 * 8;
#pragma unroll
            for (int ksg = 0; ksg < 4; ++ksg)
#pragma unroll
                for (int dt = 0; dt < 2; ++dt) {
                    asm volatile("ds_read_b64_tr_b16 %0, %2\n\t"
                                 "ds_read_b64_tr_b16 %1, %2 offset:512"
                                 : "=v"(vl[ksg][dt]), "=v"(vh[ksg][dt])
                                 : "v"(vbase + (unsigned)(ksg * 2048 + dt * 256)) : "memory");
                }
            const float mt = m2;
            float sum = 0.f;
            unsigned w[2][8];
#pragma unroll
            for (int st = 0; st < 2; ++st)
#pragma unroll
                for (int n = 0; n < 8; ++n) {
                    float e0 = __builtin_amdgcn_exp2f(fmaf(sc[st][2 * n],     CL2, -mt));
                    float e1 = __builtin_amdgcn_exp2f(fmaf(sc[st][2 * n + 1], CL2, -mt));
                    sum += e0 + e1;
                    w[st][n] = pack2bf(e0, e1);
                }
            sum += __shfl_xor(sum, 32);
            l += sum;
            union { unsigned u[4]; bf16x8 v; } pa[4];
#pragma unroll
            for (int ksg = 0; ksg < 4; ++ksg) {
                const int st = ksg >> 1, kl = ksg & 1;
                unsigned x0 = w[st][4 * kl],     y0 = w[st][4 * kl + 2];
                unsigned x1 = w[st][4 * kl + 1], y1 = w[st][4 * kl + 3];
                asm volatile("v_permlane32_swap_b32 %0, %1" : "+v"(x0), "+v"(y0));
                asm volatile("v_permlane32_swap_b32 %0, %1" : "+v"(x1), "+v"(y1));
                pa[ksg].u[0] = x0; pa[ksg].u[1] = x1; pa[ksg].u[2] = y0; pa[ksg].u[3] = y1;
            }
            asm volatile("s_waitcnt lgkmcnt(0)" ::: "memory");
            __builtin_amdgcn_sched_barrier(0);
            __builtin_amdgcn_s_setprio(1);
#pragma unroll
            for (int ksg = 0; ksg < 4; ++ksg)
#pragma unroll
                for (int dt = 0; dt < 2; ++dt) {
                    bf16x8 vb = __builtin_shufflevector(vl[ksg][dt], vh[ksg][dt],
                                                        0, 1, 2, 3, 4, 5, 6, 7);
                    acc[dt] = MFMA32(pa[ksg].v, vb, acc[dt]);
                }
            __builtin_amdgcn_s_setprio(0);
        }

        __syncthreads();
    }

    float invl = 1.f / l;
#pragma unroll
    for (int r = 0; r < 16; ++r) {
        float ir = __shfl(invl, (r & 3) + 8 * (r >> 2) + 4 * hi);
        long orow = rowbase + q0 + (r & 3) + 8 * (r >> 2) + 4 * hi;
#pragma unroll
        for (int dt = 0; dt < 2; ++dt)
            out[orow * Dd + h * HD + dt * 32 + ln31] = __float2bfloat16(acc[dt][r] * ir);
    }
}

extern "C" void kernel_launch(void* const* d_in, const int* in_sizes, int n_in,
                              void* d_out, int out_size, void* d_ws, size_t ws_size,
                              hipStream_t stream) {
    const float* x    = (const float*)d_in[0];
    const float* Wqkv = (const float*)d_in[1];
    const float* Wo_w = (const float*)d_in[2];
    const float* Wo_b = (const float*)d_in[3];
    float* out = (float*)d_out;

    const size_t MB = 1ull << 20;
    char* ws = (char*)d_ws;
    bf16* xb    = (bf16*)(ws);               // 16 MB; reused as attn output
    bf16* wqkvb = (bf16*)(ws + 16 * MB);     // 6 MB
    bf16* wob   = (bf16*)(ws + 22 * MB);     // 2 MB
    bf16* qkv   = (bf16*)(ws + 24 * MB);     // 48 MB
    bf16* attnb = xb;

    cast_all<<<12288, 256, 0, stream>>>(x, Wqkv, Wo_w, xb, wqkvb, wob);

    // qkv = x @ Wqkv^T : grid 32*24 = 768 = exactly 3 generations
    gemm256x128<true><<<(Mrows / 256) * (TD / 128), 512, 0, stream>>>(
        xb, wqkvb, qkv, nullptr, nullptr, Mrows, TD, Dd);

    attn_fwd6<<<dim3(Bb * Hh, 16), 256, 0, stream>>>(qkv, attnb);

    // out = attn @ Wo^T + b : grid 32*8 = 256 = exactly 1 generation
    gemm256x128<false><<<(Mrows / 256) * (Dd / 128), 512, 0, stream>>>(
        attnb, wob, nullptr, out, Wo_b, Mrows, Dd, Dd);
}

// Round 12
// 165.087 us; speedup vs baseline: 1.0168x; 1.0168x over previous
//
#include <hip/hip_runtime.h>
#include <hip/hip_bf16.h>

using bf16 = __hip_bfloat16;
typedef __attribute__((ext_vector_type(8))) short bf16x8;
typedef __attribute__((ext_vector_type(4))) short bf16x4;
typedef __attribute__((ext_vector_type(4))) float f32x4;
typedef __attribute__((ext_vector_type(16))) float f32x16;

static constexpr int Bb = 4, Ss = 2048, Dd = 1024, Hh = 16, HD = 64;
static constexpr int TD = 3 * Dd;            // 3072
static constexpr int Mrows = Bb * Ss;        // 8192

#define MFMA16(a, b, c) __builtin_amdgcn_mfma_f32_16x16x32_bf16((a), (b), (c), 0, 0, 0)
#define MFMA32(a, b, c) __builtin_amdgcn_mfma_f32_32x32x16_bf16((a), (b), (c), 0, 0, 0)

__device__ __forceinline__ void gload_lds16(const void* g, void* l) {
    __builtin_amdgcn_global_load_lds(
        (const __attribute__((address_space(1))) void*)g,
        (__attribute__((address_space(3))) void*)l, 16, 0, 0);
}

__device__ __forceinline__ unsigned lds_addr(const void* p) {
    return (unsigned)(unsigned long long)(const __attribute__((address_space(3))) char*)p;
}

__device__ __forceinline__ unsigned pack2bf(float a, float b) {
    bf16 x = __float2bfloat16(a), y = __float2bfloat16(b);
    return (unsigned)(*(unsigned short*)&x) | ((unsigned)(*(unsigned short*)&y) << 16);
}

// ---------------- fused cast fp32 -> bf16 (x, Wqkv, Wo in one launch) ------
__global__ void cast_all(const float* __restrict__ x, const float* __restrict__ w1,
                         const float* __restrict__ w2, bf16* __restrict__ xb,
                         bf16* __restrict__ w1b, bf16* __restrict__ w2b) {
    int i = blockIdx.x * blockDim.x + threadIdx.x;   // 4-elem groups
    const float* src; bf16* dst; int off;
    if (i < 2097152)      { src = x;  dst = xb;  off = i; }
    else if (i < 2883584) { src = w1; dst = w1b; off = i - 2097152; }
    else                  { src = w2; dst = w2b; off = i - 2883584; }
    float4 v = ((const float4*)src)[off];
    uint2 o;
    o.x = pack2bf(v.x, v.y);
    o.y = pack2bf(v.z, v.w);
    *(uint2*)(dst + 4l * off) = o;
}

// ---------------- GEMM 256x256, BK=64, 8 waves (2Mx4N), wave tile 128x64 ---
// v12: amortize the ~constant per-K-tile schedule overhead over 2x MFMA.
// Per K-tile (dbuf d = kt&1): 4 phases {ds_reads 12/4/8/0 b128; s_barrier;
// lgkmcnt(0); setprio(1); 16 MFMA; setprio(0); s_barrier}. In-buffer staging
// of kt+2 is race-free by quadrant frees: B rows fully read after q1 ->
// stage B halves at q2; A rows after q2 -> stage A halves at q3.
// vmcnt(8) once per K-tile at group top (outstanding 16 -> drains kt+1's 8,
// issued ~5 phases earlier). Never vmcnt(0) in loop. T2 XOR-swizzle.
template<bool OUT_BF16>
__global__ __launch_bounds__(512, 1) void gemm256sq(
    const bf16* __restrict__ A, const bf16* __restrict__ Bt,
    bf16* __restrict__ Cb, float* __restrict__ Cf, const float* __restrict__ bias,
    int M, int N, int K)
{
    __shared__ __align__(16) bf16 As[2][256 * 64];   // 64 KB
    __shared__ __align__(16) bf16 Bs[2][256 * 64];   // 64 KB
    const int tid = threadIdx.x;
    const int lane = tid & 63;
    const int wid = tid >> 6;
    const int lc = lane & 15, lg = lane >> 4;
    const int wm = wid >> 2, wn = wid & 3;           // 2M x 4N, wave = 128x64

    const int gx = N >> 8;
    const int nwg = gridDim.x;
    int orig = blockIdx.x;
    int swz = ((nwg & 7) == 0) ? ((orig & 7) * (nwg >> 3) + (orig >> 3)) : orig;
    const long tile_m = (long)(swz / gx) * 256;
    const long tile_n = (long)(swz % gx) * 256;

    // stage one half-tile (128 rows x 64 cols) = 2 gload_lds16/thread.
    // j4: 0 = A rows 0-127, 1 = A rows 128-255, 2 = B h0, 3 = B h1.
    auto STAGE_HALF = [&](int buf, int kt, int j4) {
        const bf16* g = (j4 < 2) ? A : Bt;
        const long tr = (j4 < 2) ? tile_m : tile_n;
        char* lds = (j4 < 2) ? (char*)As[buf] : (char*)Bs[buf];
        const int h = j4 & 1;
#pragma unroll
        for (int i = 0; i < 2; ++i) {
            int s = tid + (2 * h + i) * 512;
            int r = s >> 3;
            int cs = (s & 7) ^ (r & 7);
            gload_lds16(g + (tr + r) * (long)K + kt * 64 + cs * 8, lds + s * 16);
        }
    };
    auto LDA = [&](int buf, int mi, int ks) -> bf16x8 {
        int row = wm * 128 + mi * 16 + lc;
        int byte = (row * 128 + ks * 64 + lg * 16) ^ ((row & 7) << 4);
        return *(const bf16x8*)((const char*)As[buf] + byte);
    };
    auto LDB = [&](int buf, int nj, int ks) -> bf16x8 {
        int row = wn * 64 + nj * 16 + lc;
        int byte = (row * 128 + ks * 64 + lg * 16) ^ ((row & 7) << 4);
        return *(const bf16x8*)((const char*)Bs[buf] + byte);
    };

    const f32x4 fz = {0.f, 0.f, 0.f, 0.f};
    f32x4 acc[8][4];                                 // 128 VGPR
#pragma unroll
    for (int i = 0; i < 8; ++i)
#pragma unroll
        for (int j = 0; j < 4; ++j) acc[i][j] = fz;

    const int nkt = K >> 6;                          // 16

#define BAR()   asm volatile("s_barrier" ::: "memory")
#define LGKM0() asm volatile("s_waitcnt lgkmcnt(0)" ::: "memory")

    // prologue: kt0 -> buf0, kt1 -> buf1 (16 loads outstanding)
#pragma unroll
    for (int j = 0; j < 4; ++j) STAGE_HALF(0, 0, j);
#pragma unroll
    for (int j = 0; j < 4; ++j) STAGE_HALF(1, 1, j);

    for (int kt = 0; kt < nkt; ++kt) {
        const int d = kt & 1;
        const int ktS = (kt + 2 < nkt) ? kt + 2 : nkt - 1;  // tail: dead re-stage
        // group top: drain kt's 8 loads (leaves kt+1's 8 in flight)
        asm volatile("s_waitcnt vmcnt(8)" ::: "memory");
        BAR();
        bf16x8 alo[4][2], ahi[4][2], blo[2][2], bhi[2][2];
        // ---- q0: read alo(8) + blo(4); MFMA mi0-3 x nj0-1 ----
#pragma unroll
        for (int mi = 0; mi < 4; ++mi) { alo[mi][0] = LDA(d, mi, 0); alo[mi][1] = LDA(d, mi, 1); }
#pragma unroll
        for (int nj = 0; nj < 2; ++nj) { blo[nj][0] = LDB(d, nj, 0); blo[nj][1] = LDB(d, nj, 1); }
        BAR(); LGKM0();
        __builtin_amdgcn_s_setprio(1);
#pragma unroll
        for (int mi = 0; mi < 4; ++mi)
#pragma unroll
            for (int nj = 0; nj < 2; ++nj)
#pragma unroll
                for (int ks = 0; ks < 2; ++ks)
                    acc[mi][nj] = MFMA16(alo[mi][ks], blo[nj][ks], acc[mi][nj]);
        __builtin_amdgcn_s_setprio(0);
        BAR();
        // ---- q1: read bhi(4); MFMA mi0-3 x nj2-3 ----
#pragma unroll
        for (int nj = 0; nj < 2; ++nj) { bhi[nj][0] = LDB(d, nj + 2, 0); bhi[nj][1] = LDB(d, nj + 2, 1); }
        BAR(); LGKM0();
        __builtin_amdgcn_s_setprio(1);
#pragma unroll
        for (int mi = 0; mi < 4; ++mi)
#pragma unroll
            for (int nj = 0; nj < 2; ++nj)
#pragma unroll
                for (int ks = 0; ks < 2; ++ks)
                    acc[mi][nj + 2] = MFMA16(alo[mi][ks], bhi[nj][ks], acc[mi][nj + 2]);
        __builtin_amdgcn_s_setprio(0);
        BAR();
        // ---- q2: read ahi(8); stage B halves of kt+2 (B of dbuf d free);
        //          MFMA mi4-7 x nj2-3 ----
#pragma unroll
        for (int mi = 0; mi < 4; ++mi) { ahi[mi][0] = LDA(d, mi + 4, 0); ahi[mi][1] = LDA(d, mi + 4, 1); }
        STAGE_HALF(d, ktS, 2); STAGE_HALF(d, ktS, 3);
        BAR(); LGKM0();
        __builtin_amdgcn_s_setprio(1);
#pragma unroll
        for (int mi = 0; mi < 4; ++mi)
#pragma unroll
            for (int nj = 0; nj < 2; ++nj)
#pragma unroll
                for (int ks = 0; ks < 2; ++ks)
                    acc[mi + 4][nj + 2] = MFMA16(ahi[mi][ks], bhi[nj][ks], acc[mi + 4][nj + 2]);
        __builtin_amdgcn_s_setprio(0);
        BAR();
        // ---- q3: stage A halves of kt+2 (A of dbuf d free); MFMA mi4-7 x nj0-1 ----
        STAGE_HALF(d, ktS, 0); STAGE_HALF(d, ktS, 1);
        __builtin_amdgcn_s_setprio(1);
#pragma unroll
        for (int mi = 0; mi < 4; ++mi)
#pragma unroll
            for (int nj = 0; nj < 2; ++nj)
#pragma unroll
                for (int ks = 0; ks < 2; ++ks)
                    acc[mi + 4][nj] = MFMA16(ahi[mi][ks], blo[nj][ks], acc[mi + 4][nj]);
        __builtin_amdgcn_s_setprio(0);
        BAR();
    }
    asm volatile("s_waitcnt vmcnt(0)" ::: "memory");   // DMA must not outlive block

#undef BAR
#undef LGKM0

    // ---- epilogue ----
#pragma unroll
    for (int mi = 0; mi < 8; ++mi)
#pragma unroll
        for (int nj = 0; nj < 4; ++nj)
#pragma unroll
            for (int rr = 0; rr < 4; ++rr) {
                long row = tile_m + wm * 128 + mi * 16 + lg * 4 + rr;
                long col = tile_n + wn * 64 + nj * 16 + lc;
                float v = acc[mi][nj][rr];
                if constexpr (OUT_BF16) Cb[row * N + col] = __float2bfloat16(v);
                else                    Cf[row * N + col] = v + bias[col];
            }
}

// ---------------- GEMM 256x128 (r11, measured-good) for GEMM2 --------------
template<bool OUT_BF16>
__global__ __launch_bounds__(512, 1) void gemm256x128(
    const bf16* __restrict__ A, const bf16* __restrict__ Bt,
    bf16* __restrict__ Cb, float* __restrict__ Cf, const float* __restrict__ bias,
    int M, int N, int K)
{
    __shared__ __align__(16) bf16 As[2][256 * 64];
    __shared__ __align__(16) bf16 Bs[2][128 * 64];
    const int tid = threadIdx.x;
    const int lane = tid & 63;
    const int wid = tid >> 6;
    const int lc = lane & 15, lg = lane >> 4;
    const int wm = wid >> 1, wn = wid & 1;

    const int gx = N >> 7;
    const int nwg = gridDim.x;
    int orig = blockIdx.x;
    int swz = ((nwg & 7) == 0) ? ((orig & 7) * (nwg >> 3) + (orig >> 3)) : orig;
    const long tile_m = (long)(swz / gx) * 256;
    const long tile_n = (long)(swz % gx) * 128;

    auto STAGE6 = [&](int buf, int kt) {
#pragma unroll
        for (int i = 0; i < 4; ++i) {
            int s = tid + i * 512;
            int r = s >> 3;
            int cs = (s & 7) ^ (r & 7);
            gload_lds16(A + (tile_m + r) * (long)K + kt * 64 + cs * 8,
                        (char*)As[buf] + s * 16);
        }
#pragma unroll
        for (int i = 0; i < 2; ++i) {
            int s = tid + i * 512;
            int r = s >> 3;
            int cs = (s & 7) ^ (r & 7);
            gload_lds16(Bt + (tile_n + r) * (long)K + kt * 64 + cs * 8,
                        (char*)Bs[buf] + s * 16);
        }
    };
    auto LDA = [&](int buf, int mi, int ks) -> bf16x8 {
        int row = wm * 64 + mi * 16 + lc;
        int byte = (row * 128 + ks * 64 + lg * 16) ^ ((row & 7) << 4);
        return *(const bf16x8*)((const char*)As[buf] + byte);
    };
    auto LDB = [&](int buf, int nj, int ks) -> bf16x8 {
        int row = wn * 64 + nj * 16 + lc;
        int byte = (row * 128 + ks * 64 + lg * 16) ^ ((row & 7) << 4);
        return *(const bf16x8*)((const char*)Bs[buf] + byte);
    };

    const f32x4 fz = {0.f, 0.f, 0.f, 0.f};
    f32x4 acc[4][4];
#pragma unroll
    for (int i = 0; i < 4; ++i)
#pragma unroll
        for (int j = 0; j < 4; ++j) acc[i][j] = fz;

    const int nkt = K >> 6;

#define BAR() asm volatile("s_barrier" ::: "memory")
    auto PHASES = [&](int b) {
        bf16x8 a0[2][2], a1[2][2], b0[2][2], b1[2][2];
#pragma unroll
        for (int mi = 0; mi < 2; ++mi) { a0[mi][0] = LDA(b, mi, 0); a0[mi][1] = LDA(b, mi, 1); }
#pragma unroll
        for (int nj = 0; nj < 2; ++nj) { b0[nj][0] = LDB(b, nj, 0); b0[nj][1] = LDB(b, nj, 1); }
        BAR();
        __builtin_amdgcn_s_setprio(1);
#pragma unroll
        for (int mi = 0; mi < 2; ++mi)
#pragma unroll
            for (int nj = 0; nj < 2; ++nj)
#pragma unroll
                for (int ks = 0; ks < 2; ++ks)
                    acc[mi][nj] = MFMA16(a0[mi][ks], b0[nj][ks], acc[mi][nj]);
        __builtin_amdgcn_s_setprio(0);
        BAR();
#pragma unroll
        for (int nj = 0; nj < 2; ++nj) { b1[nj][0] = LDB(b, nj + 2, 0); b1[nj][1] = LDB(b, nj + 2, 1); }
        BAR();
        __builtin_amdgcn_s_setprio(1);
#pragma unroll
        for (int mi = 0; mi < 2; ++mi)
#pragma unroll
            for (int nj = 0; nj < 2; ++nj)
#pragma unroll
                for (int ks = 0; ks < 2; ++ks)
                    acc[mi][nj + 2] = MFMA16(a0[mi][ks], b1[nj][ks], acc[mi][nj + 2]);
        __builtin_amdgcn_s_setprio(0);
        BAR();
#pragma unroll
        for (int mi = 0; mi < 2; ++mi) { a1[mi][0] = LDA(b, mi + 2, 0); a1[mi][1] = LDA(b, mi + 2, 1); }
        BAR();
        __builtin_amdgcn_s_setprio(1);
#pragma unroll
        for (int mi = 0; mi < 2; ++mi)
#pragma unroll
            for (int nj = 0; nj < 2; ++nj)
#pragma unroll
                for (int ks = 0; ks < 2; ++ks)
                    acc[mi + 2][nj + 2] = MFMA16(a1[mi][ks], b1[nj][ks], acc[mi + 2][nj + 2]);
        __builtin_amdgcn_s_setprio(0);
        BAR();
        __builtin_amdgcn_s_setprio(1);
#pragma unroll
        for (int mi = 0; mi < 2; ++mi)
#pragma unroll
            for (int nj = 0; nj < 2; ++nj)
#pragma unroll
                for (int ks = 0; ks < 2; ++ks)
                    acc[mi + 2][nj] = MFMA16(a1[mi][ks], b0[nj][ks], acc[mi + 2][nj]);
        __builtin_amdgcn_s_setprio(0);
        BAR();
    };

    STAGE6(0, 0);
    STAGE6(1, 1);
    asm volatile("s_waitcnt vmcnt(6)" ::: "memory");
    BAR();

    for (int t = 0; t < nkt / 2; ++t) {
        const int kt0 = 2 * t, kt1 = 2 * t + 1;
        PHASES(0);
        { int sk = kt0 + 2 < nkt ? kt0 + 2 : nkt - 1; STAGE6(0, sk); }
        asm volatile("s_waitcnt vmcnt(6)" ::: "memory");
        BAR();
        PHASES(1);
        { int sk = kt1 + 2 < nkt ? kt1 + 2 : nkt - 1; STAGE6(1, sk); }
        asm volatile("s_waitcnt vmcnt(6)" ::: "memory");
        BAR();
    }
    asm volatile("s_waitcnt vmcnt(0)" ::: "memory");
#undef BAR

#pragma unroll
    for (int mi = 0; mi < 4; ++mi)
#pragma unroll
        for (int nj = 0; nj < 4; ++nj)
#pragma unroll
            for (int rr = 0; rr < 4; ++rr) {
                long row = tile_m + wm * 64 + mi * 16 + lg * 4 + rr;
                long col = tile_n + wn * 64 + nj * 16 + lc;
                float v = acc[mi][nj][rr];
                if constexpr (OUT_BF16) Cb[row * N + col] = __float2bfloat16(v);
                else                    Cf[row * N + col] = v + bias[col];
            }
}

// ---------------- causal flash attention v6: single strip, heavy-first ----
__global__ __launch_bounds__(256, 2) void attn_fwd6(const bf16* __restrict__ qkv,
                                                    bf16* __restrict__ out) {
    const int bh = blockIdx.x;                 // 0..63
    const int p  = blockIdx.y;                 // 0..15
    const int s  = 15 - p;                     // strip index, heavy first
    const int b = bh >> 4, h = bh & 15;
    const int tid = threadIdx.x;
    const int lane = tid & 63, wid = tid >> 6;
    const int ln31 = lane & 31, hi = lane >> 5;
    const int ch = (lane >> 4) & 1, c16 = lane & 15;
    const long rowbase = (long)b * Ss;
    const int q0 = s * 128 + wid * 32;         // this wave's 32 q-rows
    const int nt = 2 * s + 2;                  // causal kv tiles
    const float CL2 = 0.18033688f;             // 0.125 * log2(e)

    __shared__ __align__(16) bf16 Ks[2][64 * 64];
    __shared__ __align__(16) bf16 Vs[2][64 * 64];

    const int sK0 = tid, sK1 = tid + 256;
    const int rK0 = sK0 >> 3, cK0 = ((sK0 & 7) ^ (rK0 & 7)) * 8;
    const int rK1 = sK1 >> 3, cK1 = ((sK1 & 7) ^ (rK1 & 7)) * 8;
    const int rV0 = ((sK0 >> 5) << 2) | ((sK0 >> 1) & 3);
    const int cV0 = ((((sK0 >> 3) & 3) << 1) | (sK0 & 1)) * 8;
    const int rV1 = ((sK1 >> 5) << 2) | ((sK1 >> 1) & 3);
    const int cV1 = ((((sK1 >> 3) & 3) << 1) | (sK1 & 1)) * 8;
    const bf16* gK0 = qkv + (rowbase + rK0) * (long)TD + h * HD + Dd + cK0;
    const bf16* gK1 = qkv + (rowbase + rK1) * (long)TD + h * HD + Dd + cK1;
    const bf16* gV0 = qkv + (rowbase + rV0) * (long)TD + h * HD + 2 * Dd + cV0;
    const bf16* gV1 = qkv + (rowbase + rV1) * (long)TD + h * HD + 2 * Dd + cV1;

    auto STAGE = [&](int buf, int kt) {
        const long o = (long)kt * 64 * TD;
        gload_lds16(gK0 + o, (char*)Ks[buf] + tid * 16);
        gload_lds16(gK1 + o, (char*)Ks[buf] + 4096 + tid * 16);
        gload_lds16(gV0 + o, (char*)Vs[buf] + tid * 16);
        gload_lds16(gV1 + o, (char*)Vs[buf] + 4096 + tid * 16);
    };

    bf16x8 qa[4];
#pragma unroll
    for (int dk = 0; dk < 4; ++dk)
        qa[dk] = *(const bf16x8*)(qkv + (rowbase + q0 + ln31) * (long)TD + h * HD + dk * 16 + hi * 8);

    f32x16 acc[2];
#pragma unroll
    for (int dt = 0; dt < 2; ++dt) acc[dt] = (f32x16)0.0f;
    float m2 = -3.0e38f;
    float l = 0.f;

    STAGE(0, 0);
    __syncthreads();

    for (int kt = 0; kt < nt; ++kt) {
        const int cur = kt & 1;
        if (kt + 1 < nt) STAGE(cur ^ 1, kt + 1);

        if (kt * 64 <= q0 + 31) {
            const char* kbp = (const char*)Ks[cur];
            const char* vbp = (const char*)Vs[cur];
            f32x16 sc[2];
            __builtin_amdgcn_s_setprio(1);
#pragma unroll
            for (int st = 0; st < 2; ++st) {
                f32x16 z = (f32x16)0.0f;
                const int row = st * 32 + ln31;
                const int sw = (row & 7) << 4;
#pragma unroll
                for (int dk = 0; dk < 4; ++dk) {
                    bf16x8 ka = *(const bf16x8*)(kbp + ((row * 128 + dk * 32 + hi * 16) ^ sw));
                    z = MFMA32(ka, qa[dk], z);
                }
                sc[st] = z;
            }
            __builtin_amdgcn_s_setprio(0);
            if (kt * 64 + 63 > q0) {
                const int qg = q0 + ln31;
                const int kbase = kt * 64 + 4 * hi;
#pragma unroll
                for (int st = 0; st < 2; ++st)
#pragma unroll
                    for (int r = 0; r < 16; ++r) {
                        int kg = kbase + st * 32 + (r & 3) + 8 * (r >> 2);
                        if (kg > qg) sc[st][r] = -3.0e38f;
                    }
            }
            float mx = sc[0][0];
#pragma unroll
            for (int r = 1; r < 16; ++r) mx = fmaxf(mx, sc[0][r]);
#pragma unroll
            for (int r = 0; r < 16; ++r) mx = fmaxf(mx, sc[1][r]);
            mx = fmaxf(mx, __shfl_xor(mx, 32));
            float pmax2 = mx * CL2;
            if (__ballot(pmax2 > m2 + 8.0f)) {
                float mnew = fmaxf(m2, pmax2);
                float sf = __builtin_amdgcn_exp2f(m2 - mnew);
                m2 = mnew;
                l *= sf;
#pragma unroll
                for (int r = 0; r < 16; ++r) {
                    float sfr = __shfl(sf, (r & 3) + 8 * (r >> 2) + 4 * hi);
                    acc[0][r] *= sfr;
                    acc[1][r] *= sfr;
                }
            }
            bf16x4 vl[4][2], vh[4][2];
            const unsigned vbase = lds_addr(vbp) + hi * 1024 + ch * 128 + c16 * 8;
#pragma unroll
            for (int ksg = 0; ksg < 4; ++ksg)
#pragma unroll
                for (int dt = 0; dt < 2; ++dt) {
                    asm volatile("ds_read_b64_tr_b16 %0, %2\n\t"
                                 "ds_read_b64_tr_b16 %1, %2 offset:512"
                                 : "=v"(vl[ksg][dt]), "=v"(vh[ksg][dt])
                                 : "v"(vbase + (unsigned)(ksg * 2048 + dt * 256)) : "memory");
                }
            const float mt = m2;
            float sum = 0.f;
            unsigned w[2][8];
#pragma unroll
            for (int st = 0; st < 2; ++st)
#pragma unroll
                for (int n = 0; n < 8; ++n) {
                    float e0 = __builtin_amdgcn_exp2f(fmaf(sc[st][2 * n],     CL2, -mt));
                    float e1 = __builtin_amdgcn_exp2f(fmaf(sc[st][2 * n + 1], CL2, -mt));
                    sum += e0 + e1;
                    w[st][n] = pack2bf(e0, e1);
                }
            sum += __shfl_xor(sum, 32);
            l += sum;
            union { unsigned u[4]; bf16x8 v; } pa[4];
#pragma unroll
            for (int ksg = 0; ksg < 4; ++ksg) {
                const int st = ksg >> 1, kl = ksg & 1;
                unsigned x0 = w[st][4 * kl],     y0 = w[st][4 * kl + 2];
                unsigned x1 = w[st][4 * kl + 1], y1 = w[st][4 * kl + 3];
                asm volatile("v_permlane32_swap_b32 %0, %1" : "+v"(x0), "+v"(y0));
                asm volatile("v_permlane32_swap_b32 %0, %1" : "+v"(x1), "+v"(y1));
                pa[ksg].u[0] = x0; pa[ksg].u[1] = x1; pa[ksg].u[2] = y0; pa[ksg].u[3] = y1;
            }
            asm volatile("s_waitcnt lgkmcnt(0)" ::: "memory");
            __builtin_amdgcn_sched_barrier(0);
            __builtin_amdgcn_s_setprio(1);
#pragma unroll
            for (int ksg = 0; ksg < 4; ++ksg)
#pragma unroll
                for (int dt = 0; dt < 2; ++dt) {
                    bf16x8 vb = __builtin_shufflevector(vl[ksg][dt], vh[ksg][dt],
                                                        0, 1, 2, 3, 4, 5, 6, 7);
                    acc[dt] = MFMA32(pa[ksg].v, vb, acc[dt]);
                }
            __builtin_amdgcn_s_setprio(0);
        }

        __syncthreads();
    }

    float invl = 1.f / l;
#pragma unroll
    for (int r = 0; r < 16; ++r) {
        float ir = __shfl(invl, (r & 3) + 8 * (r >> 2) + 4 * hi);
        long orow = rowbase + q0 + (r & 3) + 8 * (r >> 2) + 4 * hi;
#pragma unroll
        for (int dt = 0; dt < 2; ++dt)
            out[orow * Dd + h * HD + dt * 32 + ln31] = __float2bfloat16(acc[dt][r] * ir);
    }
}

extern "C" void kernel_launch(void* const* d_in, const int* in_sizes, int n_in,
                              void* d_out, int out_size, void* d_ws, size_t ws_size,
                              hipStream_t stream) {
    const float* x    = (const float*)d_in[0];
    const float* Wqkv = (const float*)d_in[1];
    const float* Wo_w = (const float*)d_in[2];
    const float* Wo_b = (const float*)d_in[3];
    float* out = (float*)d_out;

    const size_t MB = 1ull << 20;
    char* ws = (char*)d_ws;
    bf16* xb    = (bf16*)(ws);               // 16 MB; reused as attn output
    bf16* wqkvb = (bf16*)(ws + 16 * MB);     // 6 MB
    bf16* wob   = (bf16*)(ws + 22 * MB);     // 2 MB
    bf16* qkv   = (bf16*)(ws + 24 * MB);     // 48 MB
    bf16* attnb = xb;

    cast_all<<<12288, 256, 0, stream>>>(x, Wqkv, Wo_w, xb, wqkvb, wob);

    // qkv = x @ Wqkv^T : 256^2 tiles, grid 32*12 = 384
    gemm256sq<true><<<(Mrows / 256) * (TD / 256), 512, 0, stream>>>(
        xb, wqkvb, qkv, nullptr, nullptr, Mrows, TD, Dd);

    attn_fwd6<<<dim3(Bb * Hh, 16), 256, 0, stream>>>(qkv, attnb);

    // out = attn @ Wo^T + b : 256x128 tiles, grid 32*8 = 256
    gemm256x128<false><<<(Mrows / 256) * (Dd / 128), 512, 0, stream>>>(
        attnb, wob, nullptr, out, Wo_b, Mrows, Dd, Dd);
}

// Round 13
// 161.578 us; speedup vs baseline: 1.0388x; 1.0217x over previous
//
#include <hip/hip_runtime.h>
#include <hip/hip_bf16.h>

using bf16 = __hip_bfloat16;
typedef __attribute__((ext_vector_type(8))) short bf16x8;
typedef __attribute__((ext_vector_type(4))) short bf16x4;
typedef __attribute__((ext_vector_type(4))) float f32x4;
typedef __attribute__((ext_vector_type(16))) float f32x16;

static constexpr int Bb = 4, Ss = 2048, Dd = 1024, Hh = 16, HD = 64;
static constexpr int TD = 3 * Dd;            // 3072
static constexpr int Mrows = Bb * Ss;        // 8192

#define MFMA16(a, b, c) __builtin_amdgcn_mfma_f32_16x16x32_bf16((a), (b), (c), 0, 0, 0)
#define MFMA32(a, b, c) __builtin_amdgcn_mfma_f32_32x32x16_bf16((a), (b), (c), 0, 0, 0)

__device__ __forceinline__ void gload_lds16(const void* g, void* l) {
    __builtin_amdgcn_global_load_lds(
        (const __attribute__((address_space(1))) void*)g,
        (__attribute__((address_space(3))) void*)l, 16, 0, 0);
}

__device__ __forceinline__ unsigned lds_addr(const void* p) {
    return (unsigned)(unsigned long long)(const __attribute__((address_space(3))) char*)p;
}

__device__ __forceinline__ unsigned pack2bf(float a, float b) {
    bf16 x = __float2bfloat16(a), y = __float2bfloat16(b);
    return (unsigned)(*(unsigned short*)&x) | ((unsigned)(*(unsigned short*)&y) << 16);
}

// ---------------- fused cast fp32 -> bf16 (x, Wqkv, Wo in one launch) ------
__global__ void cast_all(const float* __restrict__ x, const float* __restrict__ w1,
                         const float* __restrict__ w2, bf16* __restrict__ xb,
                         bf16* __restrict__ w1b, bf16* __restrict__ w2b) {
    int i = blockIdx.x * blockDim.x + threadIdx.x;   // 4-elem groups
    const float* src; bf16* dst; int off;
    if (i < 2097152)      { src = x;  dst = xb;  off = i; }
    else if (i < 2883584) { src = w1; dst = w1b; off = i - 2097152; }
    else                  { src = w2; dst = w2b; off = i - 2883584; }
    float4 v = ((const float4*)src)[off];
    uint2 o;
    o.x = pack2bf(v.x, v.y);
    o.y = pack2bf(v.z, v.w);
    *(uint2*)(dst + 4l * off) = o;
}

// ---------------- GEMM: C[m,n] = sum_k A[m,k] * Bt[n,k] ----------------
// 128x128 tile, BK=32, 4 waves, 16KB LDS. v13: __launch_bounds__(256,4)
// targets >=4 blocks/CU (16 waves) -- the m97/m114 mechanism: cross-wave
// overlap of staging stalls, not intra-wave scheduling. All six 8-10
// waves/CU schedule variants (r7-r12) pinned at ~630 TF; this tests TLP.
template<bool OUT_BF16>
__global__ __launch_bounds__(256, 4) void gemm_bt(
    const bf16* __restrict__ A, const bf16* __restrict__ Bt,
    bf16* __restrict__ Cb, float* __restrict__ Cf, const float* __restrict__ bias,
    int M, int N, int K)
{
    __shared__ __align__(16) bf16 As[128 * 32];
    __shared__ __align__(16) bf16 Bs[128 * 32];
    const int tid = threadIdx.x;
    const int lane = tid & 63, wid = tid >> 6;
    const int lc = lane & 15, lg = lane >> 4;
    const int wr = wid >> 1, wc = wid & 1;

    const int nwg = gridDim.x * gridDim.y;
    int orig = blockIdx.y * gridDim.x + blockIdx.x;
    int swz = orig;
    if ((nwg & 7) == 0) swz = (orig & 7) * (nwg >> 3) + (orig >> 3);
    const long tile_m = (long)(swz / (int)gridDim.x) * 128;
    const long tile_n = (long)(swz % (int)gridDim.x) * 128;

    const f32x4 fz = {0.f, 0.f, 0.f, 0.f};
    f32x4 acc[4][4];
#pragma unroll
    for (int i = 0; i < 4; ++i)
#pragma unroll
        for (int j = 0; j < 4; ++j) acc[i][j] = fz;

    for (int k0 = 0; k0 < K; k0 += 32) {
#pragma unroll
        for (int it = 0; it < 2; ++it) {
            int c = tid + it * 256;
            int row = c >> 2, seg = c & 3;
            gload_lds16(A  + (tile_m + row) * (long)K + k0 + seg * 8, (char*)As + c * 16);
            gload_lds16(Bt + (tile_n + row) * (long)K + k0 + seg * 8, (char*)Bs + c * 16);
        }
        __syncthreads();
        bf16x8 af[4], bfr[4];
#pragma unroll
        for (int i = 0; i < 4; ++i) {
            af[i]  = *(const bf16x8*)(As + (wr * 64 + i * 16 + lc) * 32 + lg * 8);
            bfr[i] = *(const bf16x8*)(Bs + (wc * 64 + i * 16 + lc) * 32 + lg * 8);
        }
#pragma unroll
        for (int i = 0; i < 4; ++i)
#pragma unroll
            for (int j = 0; j < 4; ++j)
                acc[i][j] = MFMA16(af[i], bfr[j], acc[i][j]);
        __syncthreads();
    }
#pragma unroll
    for (int i = 0; i < 4; ++i)
#pragma unroll
        for (int j = 0; j < 4; ++j)
#pragma unroll
            for (int r = 0; r < 4; ++r) {
                long row = tile_m + wr * 64 + i * 16 + lg * 4 + r;
                long col = tile_n + wc * 64 + j * 16 + lc;
                float v = acc[i][j][r];
                if constexpr (OUT_BF16) Cb[row * N + col] = __float2bfloat16(v);
                else                    Cf[row * N + col] = v + bias[col];
            }
}

// ---------------- causal flash attention v6: single strip, heavy-first ----
__global__ __launch_bounds__(256, 2) void attn_fwd6(const bf16* __restrict__ qkv,
                                                    bf16* __restrict__ out) {
    const int bh = blockIdx.x;                 // 0..63
    const int p  = blockIdx.y;                 // 0..15
    const int s  = 15 - p;                     // strip index, heavy first
    const int b = bh >> 4, h = bh & 15;
    const int tid = threadIdx.x;
    const int lane = tid & 63, wid = tid >> 6;
    const int ln31 = lane & 31, hi = lane >> 5;
    const int ch = (lane >> 4) & 1, c16 = lane & 15;
    const long rowbase = (long)b * Ss;
    const int q0 = s * 128 + wid * 32;         // this wave's 32 q-rows
    const int nt = 2 * s + 2;                  // causal kv tiles
    const float CL2 = 0.18033688f;             // 0.125 * log2(e)

    __shared__ __align__(16) bf16 Ks[2][64 * 64];
    __shared__ __align__(16) bf16 Vs[2][64 * 64];

    const int sK0 = tid, sK1 = tid + 256;
    const int rK0 = sK0 >> 3, cK0 = ((sK0 & 7) ^ (rK0 & 7)) * 8;
    const int rK1 = sK1 >> 3, cK1 = ((sK1 & 7) ^ (rK1 & 7)) * 8;
    const int rV0 = ((sK0 >> 5) << 2) | ((sK0 >> 1) & 3);
    const int cV0 = ((((sK0 >> 3) & 3) << 1) | (sK0 & 1)) * 8;
    const int rV1 = ((sK1 >> 5) << 2) | ((sK1 >> 1) & 3);
    const int cV1 = ((((sK1 >> 3) & 3) << 1) | (sK1 & 1)) * 8;
    const bf16* gK0 = qkv + (rowbase + rK0) * (long)TD + h * HD + Dd + cK0;
    const bf16* gK1 = qkv + (rowbase + rK1) * (long)TD + h * HD + Dd + cK1;
    const bf16* gV0 = qkv + (rowbase + rV0) * (long)TD + h * HD + 2 * Dd + cV0;
    const bf16* gV1 = qkv + (rowbase + rV1) * (long)TD + h * HD + 2 * Dd + cV1;

    auto STAGE = [&](int buf, int kt) {
        const long o = (long)kt * 64 * TD;
        gload_lds16(gK0 + o, (char*)Ks[buf] + tid * 16);
        gload_lds16(gK1 + o, (char*)Ks[buf] + 4096 + tid * 16);
        gload_lds16(gV0 + o, (char*)Vs[buf] + tid * 16);
        gload_lds16(gV1 + o, (char*)Vs[buf] + 4096 + tid * 16);
    };

    bf16x8 qa[4];
#pragma unroll
    for (int dk = 0; dk < 4; ++dk)
        qa[dk] = *(const bf16x8*)(qkv + (rowbase + q0 + ln31) * (long)TD + h * HD + dk * 16 + hi * 8);

    f32x16 acc[2];
#pragma unroll
    for (int dt = 0; dt < 2; ++dt) acc[dt] = (f32x16)0.0f;
    float m2 = -3.0e38f;
    float l = 0.f;

    STAGE(0, 0);
    __syncthreads();

    for (int kt = 0; kt < nt; ++kt) {
        const int cur = kt & 1;
        if (kt + 1 < nt) STAGE(cur ^ 1, kt + 1);

        if (kt * 64 <= q0 + 31) {
            const char* kbp = (const char*)Ks[cur];
            const char* vbp = (const char*)Vs[cur];
            f32x16 sc[2];
            __builtin_amdgcn_s_setprio(1);
#pragma unroll
            for (int st = 0; st < 2; ++st) {
                f32x16 z = (f32x16)0.0f;
                const int row = st * 32 + ln31;
                const int sw = (row & 7) << 4;
#pragma unroll
                for (int dk = 0; dk < 4; ++dk) {
                    bf16x8 ka = *(const bf16x8*)(kbp + ((row * 128 + dk * 32 + hi * 16) ^ sw));
                    z = MFMA32(ka, qa[dk], z);
                }
                sc[st] = z;
            }
            __builtin_amdgcn_s_setprio(0);
            if (kt * 64 + 63 > q0) {
                const int qg = q0 + ln31;
                const int kbase = kt * 64 + 4 * hi;
#pragma unroll
                for (int st = 0; st < 2; ++st)
#pragma unroll
                    for (int r = 0; r < 16; ++r) {
                        int kg = kbase + st * 32 + (r & 3) + 8 * (r >> 2);
                        if (kg > qg) sc[st][r] = -3.0e38f;
                    }
            }
            float mx = sc[0][0];
#pragma unroll
            for (int r = 1; r < 16; ++r) mx = fmaxf(mx, sc[0][r]);
#pragma unroll
            for (int r = 0; r < 16; ++r) mx = fmaxf(mx, sc[1][r]);
            mx = fmaxf(mx, __shfl_xor(mx, 32));
            float pmax2 = mx * CL2;
            if (__ballot(pmax2 > m2 + 8.0f)) {
                float mnew = fmaxf(m2, pmax2);
                float sf = __builtin_amdgcn_exp2f(m2 - mnew);
                m2 = mnew;
                l *= sf;
#pragma unroll
                for (int r = 0; r < 16; ++r) {
                    float sfr = __shfl(sf, (r & 3) + 8 * (r >> 2) + 4 * hi);
                    acc[0][r] *= sfr;
                    acc[1][r] *= sfr;
                }
            }
            bf16x4 vl[4][2], vh[4][2];
            const unsigned vbase = lds_addr(vbp) + hi * 1024 + ch * 128 + c16 * 8;
#pragma unroll
            for (int ksg = 0; ksg < 4; ++ksg)
#pragma unroll
                for (int dt = 0; dt < 2; ++dt) {
                    asm volatile("ds_read_b64_tr_b16 %0, %2\n\t"
                                 "ds_read_b64_tr_b16 %1, %2 offset:512"
                                 : "=v"(vl[ksg][dt]), "=v"(vh[ksg][dt])
                                 : "v"(vbase + (unsigned)(ksg * 2048 + dt * 256)) : "memory");
                }
            const float mt = m2;
            float sum = 0.f;
            unsigned w[2][8];
#pragma unroll
            for (int st = 0; st < 2; ++st)
#pragma unroll
                for (int n = 0; n < 8; ++n) {
                    float e0 = __builtin_amdgcn_exp2f(fmaf(sc[st][2 * n],     CL2, -mt));
                    float e1 = __builtin_amdgcn_exp2f(fmaf(sc[st][2 * n + 1], CL2, -mt));
                    sum += e0 + e1;
                    w[st][n] = pack2bf(e0, e1);
                }
            sum += __shfl_xor(sum, 32);
            l += sum;
            union { unsigned u[4]; bf16x8 v; } pa[4];
#pragma unroll
            for (int ksg = 0; ksg < 4; ++ksg) {
                const int st = ksg >> 1, kl = ksg & 1;
                unsigned x0 = w[st][4 * kl],     y0 = w[st][4 * kl + 2];
                unsigned x1 = w[st][4 * kl + 1], y1 = w[st][4 * kl + 3];
                asm volatile("v_permlane32_swap_b32 %0, %1" : "+v"(x0), "+v"(y0));
                asm volatile("v_permlane32_swap_b32 %0, %1" : "+v"(x1), "+v"(y1));
                pa[ksg].u[0] = x0; pa[ksg].u[1] = x1; pa[ksg].u[2] = y0; pa[ksg].u[3] = y1;
            }
            asm volatile("s_waitcnt lgkmcnt(0)" ::: "memory");
            __builtin_amdgcn_sched_barrier(0);
            __builtin_amdgcn_s_setprio(1);
#pragma unroll
            for (int ksg = 0; ksg < 4; ++ksg)
#pragma unroll
                for (int dt = 0; dt < 2; ++dt) {
                    bf16x8 vb = __builtin_shufflevector(vl[ksg][dt], vh[ksg][dt],
                                                        0, 1, 2, 3, 4, 5, 6, 7);
                    acc[dt] = MFMA32(pa[ksg].v, vb, acc[dt]);
                }
            __builtin_amdgcn_s_setprio(0);
        }

        __syncthreads();
    }

    float invl = 1.f / l;
#pragma unroll
    for (int r = 0; r < 16; ++r) {
        float ir = __shfl(invl, (r & 3) + 8 * (r >> 2) + 4 * hi);
        long orow = rowbase + q0 + (r & 3) + 8 * (r >> 2) + 4 * hi;
#pragma unroll
        for (int dt = 0; dt < 2; ++dt)
            out[orow * Dd + h * HD + dt * 32 + ln31] = __float2bfloat16(acc[dt][r] * ir);
    }
}

extern "C" void kernel_launch(void* const* d_in, const int* in_sizes, int n_in,
                              void* d_out, int out_size, void* d_ws, size_t ws_size,
                              hipStream_t stream) {
    const float* x    = (const float*)d_in[0];
    const float* Wqkv = (const float*)d_in[1];
    const float* Wo_w = (const float*)d_in[2];
    const float* Wo_b = (const float*)d_in[3];
    float* out = (float*)d_out;

    const size_t MB = 1ull << 20;
    char* ws = (char*)d_ws;
    bf16* xb    = (bf16*)(ws);               // 16 MB; reused as attn output
    bf16* wqkvb = (bf16*)(ws + 16 * MB);     // 6 MB
    bf16* wob   = (bf16*)(ws + 22 * MB);     // 2 MB
    bf16* qkv   = (bf16*)(ws + 24 * MB);     // 48 MB
    bf16* attnb = xb;

    cast_all<<<12288, 256, 0, stream>>>(x, Wqkv, Wo_w, xb, wqkvb, wob);

    // qkv = x @ Wqkv^T : 128^2 tiles, grid 24*64 = 1536 (6 blocks/CU)
    gemm_bt<true><<<dim3(TD / 128, Mrows / 128), 256, 0, stream>>>(
        xb, wqkvb, qkv, nullptr, nullptr, Mrows, TD, Dd);

    attn_fwd6<<<dim3(Bb * Hh, 16), 256, 0, stream>>>(qkv, attnb);

    // out = attn @ Wo^T + b : grid 8*64 = 512 (2 blocks/CU)
    gemm_bt<false><<<dim3(Dd / 128, Mrows / 128), 256, 0, stream>>>(
        attnb, wob, nullptr, out, Wo_b, Mrows, Dd, Dd);
}

// Round 14
// 146.836 us; speedup vs baseline: 1.1431x; 1.1004x over previous
//
#include <hip/hip_runtime.h>
#include <hip/hip_bf16.h>

using bf16 = __hip_bfloat16;
typedef __attribute__((ext_vector_type(8))) short bf16x8;
typedef __attribute__((ext_vector_type(4))) short bf16x4;
typedef __attribute__((ext_vector_type(4))) float f32x4;
typedef __attribute__((ext_vector_type(16))) float f32x16;

static constexpr int Bb = 4, Ss = 2048, Dd = 1024, Hh = 16, HD = 64;
static constexpr int TD = 3 * Dd;            // 3072
static constexpr int Mrows = Bb * Ss;        // 8192

#define MFMA16(a, b, c) __builtin_amdgcn_mfma_f32_16x16x32_bf16((a), (b), (c), 0, 0, 0)
#define MFMA32(a, b, c) __builtin_amdgcn_mfma_f32_32x32x16_bf16((a), (b), (c), 0, 0, 0)

__device__ __forceinline__ void gload_lds16(const void* g, void* l) {
    __builtin_amdgcn_global_load_lds(
        (const __attribute__((address_space(1))) void*)g,
        (__attribute__((address_space(3))) void*)l, 16, 0, 0);
}

__device__ __forceinline__ unsigned lds_addr(const void* p) {
    return (unsigned)(unsigned long long)(const __attribute__((address_space(3))) char*)p;
}

__device__ __forceinline__ unsigned pack2bf(float a, float b) {
    bf16 x = __float2bfloat16(a), y = __float2bfloat16(b);
    return (unsigned)(*(unsigned short*)&x) | ((unsigned)(*(unsigned short*)&y) << 16);
}

// ---------------- fused cast fp32 -> bf16 (x, Wqkv, Wo in one launch) ------
__global__ void cast_all(const float* __restrict__ x, const float* __restrict__ w1,
                         const float* __restrict__ w2, bf16* __restrict__ xb,
                         bf16* __restrict__ w1b, bf16* __restrict__ w2b) {
    int i = blockIdx.x * blockDim.x + threadIdx.x;   // 4-elem groups
    const float* src; bf16* dst; int off;
    if (i < 2097152)      { src = x;  dst = xb;  off = i; }
    else if (i < 2883584) { src = w1; dst = w1b; off = i - 2097152; }
    else                  { src = w2; dst = w2b; off = i - 2883584; }
    float4 v = ((const float4*)src)[off];
    uint2 o;
    o.x = pack2bf(v.x, v.y);
    o.y = pack2bf(v.z, v.w);
    *(uint2*)(dst + 4l * off) = o;
}

// ---------------- GEMM: C[m,n] = sum_k A[m,k] * Bt[n,k] ----------------
// v14 = r13 with ONE change: BK=64 + XOR-swizzled LDS (128B rows).
// r13's fragment reads were 8-way bank-conflicted (64B rows: lanes lc=0..15
// hit banks {0,16} per quarter-wave; 6.3M conflicts, LDS ~saturated at
// ~1022cy/K-iter). 128B rows + byte ^= (row&7)<<4 makes quarter-wave reads
// 2-way max (= free, m136) -- the exact pattern measured at 0 conflicts in
// r8-r12. Simple m97-style 2-barrier loop, single-buffered 32KB LDS ->
// 5 blocks/CU; cross-block TLP hides staging (m114 mechanism).
// ks-loop outer keeps live frags at 8x bf16x8 = 32 VGPR (no spill at 128 cap).
template<bool OUT_BF16>
__global__ __launch_bounds__(256, 4) void gemm_bt(
    const bf16* __restrict__ A, const bf16* __restrict__ Bt,
    bf16* __restrict__ Cb, float* __restrict__ Cf, const float* __restrict__ bias,
    int M, int N, int K)
{
    __shared__ __align__(16) bf16 As[128 * 64];   // 16 KB
    __shared__ __align__(16) bf16 Bs[128 * 64];   // 16 KB
    const int tid = threadIdx.x;
    const int lane = tid & 63, wid = tid >> 6;
    const int lc = lane & 15, lg = lane >> 4;
    const int wr = wid >> 1, wc = wid & 1;

    const int nwg = gridDim.x * gridDim.y;
    int orig = blockIdx.y * gridDim.x + blockIdx.x;
    int swz = orig;
    if ((nwg & 7) == 0) swz = (orig & 7) * (nwg >> 3) + (orig >> 3);
    const long tile_m = (long)(swz / (int)gridDim.x) * 128;
    const long tile_n = (long)(swz % (int)gridDim.x) * 128;

    const f32x4 fz = {0.f, 0.f, 0.f, 0.f};
    f32x4 acc[4][4];
#pragma unroll
    for (int i = 0; i < 4; ++i)
#pragma unroll
        for (int j = 0; j < 4; ++j) acc[i][j] = fz;

    for (int k0 = 0; k0 < K; k0 += 64) {
        // stage: 1024 slots of 16B per matrix; LDS linear in slot s,
        // global col-seg pre-swizzled: cs = (s&7)^(r&7)  (G21 involution)
#pragma unroll
        for (int it = 0; it < 4; ++it) {
            int s = tid + it * 256;
            int r = s >> 3;
            int cs = (s & 7) ^ (r & 7);
            gload_lds16(A  + (tile_m + r) * (long)K + k0 + cs * 8, (char*)As + s * 16);
            gload_lds16(Bt + (tile_n + r) * (long)K + k0 + cs * 8, (char*)Bs + s * 16);
        }
        __syncthreads();
#pragma unroll
        for (int ks = 0; ks < 2; ++ks) {
            bf16x8 af[4], bfr[4];
#pragma unroll
            for (int i = 0; i < 4; ++i) {
                int rowa = wr * 64 + i * 16 + lc;
                af[i] = *(const bf16x8*)((const char*)As +
                        ((rowa * 128 + ks * 64 + lg * 16) ^ ((rowa & 7) << 4)));
                int rowb = wc * 64 + i * 16 + lc;
                bfr[i] = *(const bf16x8*)((const char*)Bs +
                        ((rowb * 128 + ks * 64 + lg * 16) ^ ((rowb & 7) << 4)));
            }
#pragma unroll
            for (int i = 0; i < 4; ++i)
#pragma unroll
                for (int j = 0; j < 4; ++j)
                    acc[i][j] = MFMA16(af[i], bfr[j], acc[i][j]);
        }
        __syncthreads();
    }
#pragma unroll
    for (int i = 0; i < 4; ++i)
#pragma unroll
        for (int j = 0; j < 4; ++j)
#pragma unroll
            for (int r = 0; r < 4; ++r) {
                long row = tile_m + wr * 64 + i * 16 + lg * 4 + r;
                long col = tile_n + wc * 64 + j * 16 + lc;
                float v = acc[i][j][r];
                if constexpr (OUT_BF16) Cb[row * N + col] = __float2bfloat16(v);
                else                    Cf[row * N + col] = v + bias[col];
            }
}

// ---------------- causal flash attention v6: single strip, heavy-first ----
__global__ __launch_bounds__(256, 2) void attn_fwd6(const bf16* __restrict__ qkv,
                                                    bf16* __restrict__ out) {
    const int bh = blockIdx.x;                 // 0..63
    const int p  = blockIdx.y;                 // 0..15
    const int s  = 15 - p;                     // strip index, heavy first
    const int b = bh >> 4, h = bh & 15;
    const int tid = threadIdx.x;
    const int lane = tid & 63, wid = tid >> 6;
    const int ln31 = lane & 31, hi = lane >> 5;
    const int ch = (lane >> 4) & 1, c16 = lane & 15;
    const long rowbase = (long)b * Ss;
    const int q0 = s * 128 + wid * 32;         // this wave's 32 q-rows
    const int nt = 2 * s + 2;                  // causal kv tiles
    const float CL2 = 0.18033688f;             // 0.125 * log2(e)

    __shared__ __align__(16) bf16 Ks[2][64 * 64];
    __shared__ __align__(16) bf16 Vs[2][64 * 64];

    const int sK0 = tid, sK1 = tid + 256;
    const int rK0 = sK0 >> 3, cK0 = ((sK0 & 7) ^ (rK0 & 7)) * 8;
    const int rK1 = sK1 >> 3, cK1 = ((sK1 & 7) ^ (rK1 & 7)) * 8;
    const int rV0 = ((sK0 >> 5) << 2) | ((sK0 >> 1) & 3);
    const int cV0 = ((((sK0 >> 3) & 3) << 1) | (sK0 & 1)) * 8;
    const int rV1 = ((sK1 >> 5) << 2) | ((sK1 >> 1) & 3);
    const int cV1 = ((((sK1 >> 3) & 3) << 1) | (sK1 & 1)) * 8;
    const bf16* gK0 = qkv + (rowbase + rK0) * (long)TD + h * HD + Dd + cK0;
    const bf16* gK1 = qkv + (rowbase + rK1) * (long)TD + h * HD + Dd + cK1;
    const bf16* gV0 = qkv + (rowbase + rV0) * (long)TD + h * HD + 2 * Dd + cV0;
    const bf16* gV1 = qkv + (rowbase + rV1) * (long)TD + h * HD + 2 * Dd + cV1;

    auto STAGE = [&](int buf, int kt) {
        const long o = (long)kt * 64 * TD;
        gload_lds16(gK0 + o, (char*)Ks[buf] + tid * 16);
        gload_lds16(gK1 + o, (char*)Ks[buf] + 4096 + tid * 16);
        gload_lds16(gV0 + o, (char*)Vs[buf] + tid * 16);
        gload_lds16(gV1 + o, (char*)Vs[buf] + 4096 + tid * 16);
    };

    bf16x8 qa[4];
#pragma unroll
    for (int dk = 0; dk < 4; ++dk)
        qa[dk] = *(const bf16x8*)(qkv + (rowbase + q0 + ln31) * (long)TD + h * HD + dk * 16 + hi * 8);

    f32x16 acc[2];
#pragma unroll
    for (int dt = 0; dt < 2; ++dt) acc[dt] = (f32x16)0.0f;
    float m2 = -3.0e38f;
    float l = 0.f;

    STAGE(0, 0);
    __syncthreads();

    for (int kt = 0; kt < nt; ++kt) {
        const int cur = kt & 1;
        if (kt + 1 < nt) STAGE(cur ^ 1, kt + 1);

        if (kt * 64 <= q0 + 31) {
            const char* kbp = (const char*)Ks[cur];
            const char* vbp = (const char*)Vs[cur];
            f32x16 sc[2];
            __builtin_amdgcn_s_setprio(1);
#pragma unroll
            for (int st = 0; st < 2; ++st) {
                f32x16 z = (f32x16)0.0f;
                const int row = st * 32 + ln31;
                const int sw = (row & 7) << 4;
#pragma unroll
                for (int dk = 0; dk < 4; ++dk) {
                    bf16x8 ka = *(const bf16x8*)(kbp + ((row * 128 + dk * 32 + hi * 16) ^ sw));
                    z = MFMA32(ka, qa[dk], z);
                }
                sc[st] = z;
            }
            __builtin_amdgcn_s_setprio(0);
            if (kt * 64 + 63 > q0) {
                const int qg = q0 + ln31;
                const int kbase = kt * 64 + 4 * hi;
#pragma unroll
                for (int st = 0; st < 2; ++st)
#pragma unroll
                    for (int r = 0; r < 16; ++r) {
                        int kg = kbase + st * 32 + (r & 3) + 8 * (r >> 2);
                        if (kg > qg) sc[st][r] = -3.0e38f;
                    }
            }
            float mx = sc[0][0];
#pragma unroll
            for (int r = 1; r < 16; ++r) mx = fmaxf(mx, sc[0][r]);
#pragma unroll
            for (int r = 0; r < 16; ++r) mx = fmaxf(mx, sc[1][r]);
            mx = fmaxf(mx, __shfl_xor(mx, 32));
            float pmax2 = mx * CL2;
            if (__ballot(pmax2 > m2 + 8.0f)) {
                float mnew = fmaxf(m2, pmax2);
                float sf = __builtin_amdgcn_exp2f(m2 - mnew);
                m2 = mnew;
                l *= sf;
#pragma unroll
                for (int r = 0; r < 16; ++r) {
                    float sfr = __shfl(sf, (r & 3) + 8 * (r >> 2) + 4 * hi);
                    acc[0][r] *= sfr;
                    acc[1][r] *= sfr;
                }
            }
            bf16x4 vl[4][2], vh[4][2];
            const unsigned vbase = lds_addr(vbp) + hi * 1024 + ch * 128 + c16 * 8;
#pragma unroll
            for (int ksg = 0; ksg < 4; ++ksg)
#pragma unroll
                for (int dt = 0; dt < 2; ++dt) {
                    asm volatile("ds_read_b64_tr_b16 %0, %2\n\t"
                                 "ds_read_b64_tr_b16 %1, %2 offset:512"
                                 : "=v"(vl[ksg][dt]), "=v"(vh[ksg][dt])
                                 : "v"(vbase + (unsigned)(ksg * 2048 + dt * 256)) : "memory");
                }
            const float mt = m2;
            float sum = 0.f;
            unsigned w[2][8];
#pragma unroll
            for (int st = 0; st < 2; ++st)
#pragma unroll
                for (int n = 0; n < 8; ++n) {
                    float e0 = __builtin_amdgcn_exp2f(fmaf(sc[st][2 * n],     CL2, -mt));
                    float e1 = __builtin_amdgcn_exp2f(fmaf(sc[st][2 * n + 1], CL2, -mt));
                    sum += e0 + e1;
                    w[st][n] = pack2bf(e0, e1);
                }
            sum += __shfl_xor(sum, 32);
            l += sum;
            union { unsigned u[4]; bf16x8 v; } pa[4];
#pragma unroll
            for (int ksg = 0; ksg < 4; ++ksg) {
                const int st = ksg >> 1, kl = ksg & 1;
                unsigned x0 = w[st][4 * kl],     y0 = w[st][4 * kl + 2];
                unsigned x1 = w[st][4 * kl + 1], y1 = w[st][4 * kl + 3];
                asm volatile("v_permlane32_swap_b32 %0, %1" : "+v"(x0), "+v"(y0));
                asm volatile("v_permlane32_swap_b32 %0, %1" : "+v"(x1), "+v"(y1));
                pa[ksg].u[0] = x0; pa[ksg].u[1] = x1; pa[ksg].u[2] = y0; pa[ksg].u[3] = y1;
            }
            asm volatile("s_waitcnt lgkmcnt(0)" ::: "memory");
            __builtin_amdgcn_sched_barrier(0);
            __builtin_amdgcn_s_setprio(1);
#pragma unroll
            for (int ksg = 0; ksg < 4; ++ksg)
#pragma unroll
                for (int dt = 0; dt < 2; ++dt) {
                    bf16x8 vb = __builtin_shufflevector(vl[ksg][dt], vh[ksg][dt],
                                                        0, 1, 2, 3, 4, 5, 6, 7);
                    acc[dt] = MFMA32(pa[ksg].v, vb, acc[dt]);
                }
            __builtin_amdgcn_s_setprio(0);
        }

        __syncthreads();
    }

    float invl = 1.f / l;
#pragma unroll
    for (int r = 0; r < 16; ++r) {
        float ir = __shfl(invl, (r & 3) + 8 * (r >> 2) + 4 * hi);
        long orow = rowbase + q0 + (r & 3) + 8 * (r >> 2) + 4 * hi;
#pragma unroll
        for (int dt = 0; dt < 2; ++dt)
            out[orow * Dd + h * HD + dt * 32 + ln31] = __float2bfloat16(acc[dt][r] * ir);
    }
}

extern "C" void kernel_launch(void* const* d_in, const int* in_sizes, int n_in,
                              void* d_out, int out_size, void* d_ws, size_t ws_size,
                              hipStream_t stream) {
    const float* x    = (const float*)d_in[0];
    const float* Wqkv = (const float*)d_in[1];
    const float* Wo_w = (const float*)d_in[2];
    const float* Wo_b = (const float*)d_in[3];
    float* out = (float*)d_out;

    const size_t MB = 1ull << 20;
    char* ws = (char*)d_ws;
    bf16* xb    = (bf16*)(ws);               // 16 MB; reused as attn output
    bf16* wqkvb = (bf16*)(ws + 16 * MB);     // 6 MB
    bf16* wob   = (bf16*)(ws + 22 * MB);     // 2 MB
    bf16* qkv   = (bf16*)(ws + 24 * MB);     // 48 MB
    bf16* attnb = xb;

    cast_all<<<12288, 256, 0, stream>>>(x, Wqkv, Wo_w, xb, wqkvb, wob);

    // qkv = x @ Wqkv^T : 128^2 tiles, grid 24*64 = 1536
    gemm_bt<true><<<dim3(TD / 128, Mrows / 128), 256, 0, stream>>>(
        xb, wqkvb, qkv, nullptr, nullptr, Mrows, TD, Dd);

    attn_fwd6<<<dim3(Bb * Hh, 16), 256, 0, stream>>>(qkv, attnb);

    // out = attn @ Wo^T + b : grid 8*64 = 512
    gemm_bt<false><<<dim3(Dd / 128, Mrows / 128), 256, 0, stream>>>(
        attnb, wob, nullptr, out, Wo_b, Mrows, Dd, Dd);
}

// Round 15
// 146.233 us; speedup vs baseline: 1.1478x; 1.0041x over previous
//
#include <hip/hip_runtime.h>
#include <hip/hip_bf16.h>

using bf16 = __hip_bfloat16;
typedef __attribute__((ext_vector_type(8))) short bf16x8;
typedef __attribute__((ext_vector_type(4))) short bf16x4;
typedef __attribute__((ext_vector_type(4))) float f32x4;
typedef __attribute__((ext_vector_type(16))) float f32x16;

static constexpr int Bb = 4, Ss = 2048, Dd = 1024, Hh = 16, HD = 64;
static constexpr int TD = 3 * Dd;            // 3072
static constexpr int Mrows = Bb * Ss;        // 8192

#define MFMA16(a, b, c) __builtin_amdgcn_mfma_f32_16x16x32_bf16((a), (b), (c), 0, 0, 0)
#define MFMA32(a, b, c) __builtin_amdgcn_mfma_f32_32x32x16_bf16((a), (b), (c), 0, 0, 0)

__device__ __forceinline__ void gload_lds16(const void* g, void* l) {
    __builtin_amdgcn_global_load_lds(
        (const __attribute__((address_space(1))) void*)g,
        (__attribute__((address_space(3))) void*)l, 16, 0, 0);
}

__device__ __forceinline__ unsigned lds_addr(const void* p) {
    return (unsigned)(unsigned long long)(const __attribute__((address_space(3))) char*)p;
}

__device__ __forceinline__ unsigned pack2bf(float a, float b) {
    bf16 x = __float2bfloat16(a), y = __float2bfloat16(b);
    return (unsigned)(*(unsigned short*)&x) | ((unsigned)(*(unsigned short*)&y) << 16);
}

// ---------------- fused cast fp32 -> bf16 (x, Wqkv, Wo in one launch) ------
__global__ void cast_all(const float* __restrict__ x, const float* __restrict__ w1,
                         const float* __restrict__ w2, bf16* __restrict__ xb,
                         bf16* __restrict__ w1b, bf16* __restrict__ w2b) {
    int i = blockIdx.x * blockDim.x + threadIdx.x;   // 4-elem groups
    const float* src; bf16* dst; int off;
    if (i < 2097152)      { src = x;  dst = xb;  off = i; }
    else if (i < 2883584) { src = w1; dst = w1b; off = i - 2097152; }
    else                  { src = w2; dst = w2b; off = i - 2883584; }
    float4 v = ((const float4*)src)[off];
    uint2 o;
    o.x = pack2bf(v.x, v.y);
    o.y = pack2bf(v.z, v.w);
    *(uint2*)(dst + 4l * off) = o;
}

// ---------------- GEMM: C[m,n] = sum_k A[m,k] * Bt[n,k] ----------------
// v14 (proven r14 win): 128x128 tile, BK=64, XOR-swizzled LDS (128B rows),
// simple 2-barrier loop, 32KB LDS, (256,4). Conflicts 6.3M -> ~0.
template<bool OUT_BF16>
__global__ __launch_bounds__(256, 4) void gemm_bt(
    const bf16* __restrict__ A, const bf16* __restrict__ Bt,
    bf16* __restrict__ Cb, float* __restrict__ Cf, const float* __restrict__ bias,
    int M, int N, int K)
{
    __shared__ __align__(16) bf16 As[128 * 64];   // 16 KB
    __shared__ __align__(16) bf16 Bs[128 * 64];   // 16 KB
    const int tid = threadIdx.x;
    const int lane = tid & 63, wid = tid >> 6;
    const int lc = lane & 15, lg = lane >> 4;
    const int wr = wid >> 1, wc = wid & 1;

    const int nwg = gridDim.x * gridDim.y;
    int orig = blockIdx.y * gridDim.x + blockIdx.x;
    int swz = orig;
    if ((nwg & 7) == 0) swz = (orig & 7) * (nwg >> 3) + (orig >> 3);
    const long tile_m = (long)(swz / (int)gridDim.x) * 128;
    const long tile_n = (long)(swz % (int)gridDim.x) * 128;

    const f32x4 fz = {0.f, 0.f, 0.f, 0.f};
    f32x4 acc[4][4];
#pragma unroll
    for (int i = 0; i < 4; ++i)
#pragma unroll
        for (int j = 0; j < 4; ++j) acc[i][j] = fz;

    for (int k0 = 0; k0 < K; k0 += 64) {
#pragma unroll
        for (int it = 0; it < 4; ++it) {
            int s = tid + it * 256;
            int r = s >> 3;
            int cs = (s & 7) ^ (r & 7);
            gload_lds16(A  + (tile_m + r) * (long)K + k0 + cs * 8, (char*)As + s * 16);
            gload_lds16(Bt + (tile_n + r) * (long)K + k0 + cs * 8, (char*)Bs + s * 16);
        }
        __syncthreads();
#pragma unroll
        for (int ks = 0; ks < 2; ++ks) {
            bf16x8 af[4], bfr[4];
#pragma unroll
            for (int i = 0; i < 4; ++i) {
                int rowa = wr * 64 + i * 16 + lc;
                af[i] = *(const bf16x8*)((const char*)As +
                        ((rowa * 128 + ks * 64 + lg * 16) ^ ((rowa & 7) << 4)));
                int rowb = wc * 64 + i * 16 + lc;
                bfr[i] = *(const bf16x8*)((const char*)Bs +
                        ((rowb * 128 + ks * 64 + lg * 16) ^ ((rowb & 7) << 4)));
            }
#pragma unroll
            for (int i = 0; i < 4; ++i)
#pragma unroll
                for (int j = 0; j < 4; ++j)
                    acc[i][j] = MFMA16(af[i], bfr[j], acc[i][j]);
        }
        __syncthreads();
    }
#pragma unroll
    for (int i = 0; i < 4; ++i)
#pragma unroll
        for (int j = 0; j < 4; ++j)
#pragma unroll
            for (int r = 0; r < 4; ++r) {
                long row = tile_m + wr * 64 + i * 16 + lg * 4 + r;
                long col = tile_n + wc * 64 + j * 16 + lc;
                float v = acc[i][j][r];
                if constexpr (OUT_BF16) Cb[row * N + col] = __float2bfloat16(v);
                else                    Cf[row * N + col] = v + bias[col];
            }
}

// ---------------- causal flash attention v7: depth-2 counted-vmcnt --------
// v6 + ONE change: 3-buffer K/V rotation, STAGE(kt+2) issued at iter top,
// end-of-iter waits vmcnt(4) = kt+1's loads (issued one FULL iteration,
// ~2.5k cy, earlier -> wait is free) + raw s_barrier. v6's __syncthreads
// drained vmcnt(0) for loads issued ~600cy earlier in the SAME iter ->
// ~300-900cy HBM exposure per tile (the m97 barrier-drain stall; T4 fix
// measured +38-73% on GEMM, m218). Buffer (kt+2)%3 = (kt-1)%3 is free:
// its reads finished before the previous end-of-iter barrier.
__global__ __launch_bounds__(256, 2) void attn_fwd7(const bf16* __restrict__ qkv,
                                                    bf16* __restrict__ out) {
    const int bh = blockIdx.x;                 // 0..63
    const int p  = blockIdx.y;                 // 0..15
    const int s  = 15 - p;                     // strip index, heavy first
    const int b = bh >> 4, h = bh & 15;
    const int tid = threadIdx.x;
    const int lane = tid & 63, wid = tid >> 6;
    const int ln31 = lane & 31, hi = lane >> 5;
    const int ch = (lane >> 4) & 1, c16 = lane & 15;
    const long rowbase = (long)b * Ss;
    const int q0 = s * 128 + wid * 32;         // this wave's 32 q-rows
    const int nt = 2 * s + 2;                  // causal kv tiles (>= 2)
    const float CL2 = 0.18033688f;             // 0.125 * log2(e)

    __shared__ __align__(16) bf16 Ks[3][64 * 64];   // 24 KB
    __shared__ __align__(16) bf16 Vs[3][64 * 64];   // 24 KB

    const int sK0 = tid, sK1 = tid + 256;
    const int rK0 = sK0 >> 3, cK0 = ((sK0 & 7) ^ (rK0 & 7)) * 8;
    const int rK1 = sK1 >> 3, cK1 = ((sK1 & 7) ^ (rK1 & 7)) * 8;
    const int rV0 = ((sK0 >> 5) << 2) | ((sK0 >> 1) & 3);
    const int cV0 = ((((sK0 >> 3) & 3) << 1) | (sK0 & 1)) * 8;
    const int rV1 = ((sK1 >> 5) << 2) | ((sK1 >> 1) & 3);
    const int cV1 = ((((sK1 >> 3) & 3) << 1) | (sK1 & 1)) * 8;
    const bf16* gK0 = qkv + (rowbase + rK0) * (long)TD + h * HD + Dd + cK0;
    const bf16* gK1 = qkv + (rowbase + rK1) * (long)TD + h * HD + Dd + cK1;
    const bf16* gV0 = qkv + (rowbase + rV0) * (long)TD + h * HD + 2 * Dd + cV0;
    const bf16* gV1 = qkv + (rowbase + rV1) * (long)TD + h * HD + 2 * Dd + cV1;

    auto STAGE = [&](int buf, int kt) {
        const long o = (long)kt * 64 * TD;
        gload_lds16(gK0 + o, (char*)Ks[buf] + tid * 16);
        gload_lds16(gK1 + o, (char*)Ks[buf] + 4096 + tid * 16);
        gload_lds16(gV0 + o, (char*)Vs[buf] + tid * 16);
        gload_lds16(gV1 + o, (char*)Vs[buf] + 4096 + tid * 16);
    };

    bf16x8 qa[4];
#pragma unroll
    for (int dk = 0; dk < 4; ++dk)
        qa[dk] = *(const bf16x8*)(qkv + (rowbase + q0 + ln31) * (long)TD + h * HD + dk * 16 + hi * 8);

    f32x16 acc[2];
#pragma unroll
    for (int dt = 0; dt < 2; ++dt) acc[dt] = (f32x16)0.0f;
    float m2 = -3.0e38f;
    float l = 0.f;

    // prologue: tiles 0,1 staged; drain tile 0's 4 loads (leave tile 1's)
    STAGE(0, 0);
    STAGE(1, 1);
    asm volatile("s_waitcnt vmcnt(4)" ::: "memory");
    asm volatile("s_barrier" ::: "memory");

    int cur = 0;                                // kt % 3
    for (int kt = 0; kt < nt; ++kt) {
        const bool pf = (kt + 2 < nt);
        if (pf) {
            int nxt = cur + 2; if (nxt >= 3) nxt -= 3;   // (kt+2)%3 == (kt-1)%3: free
            STAGE(nxt, kt + 2);
        }

        if (kt * 64 <= q0 + 31) {
            const char* kbp = (const char*)Ks[cur];
            const char* vbp = (const char*)Vs[cur];
            f32x16 sc[2];
            __builtin_amdgcn_s_setprio(1);
#pragma unroll
            for (int st = 0; st < 2; ++st) {
                f32x16 z = (f32x16)0.0f;
                const int row = st * 32 + ln31;
                const int sw = (row & 7) << 4;
#pragma unroll
                for (int dk = 0; dk < 4; ++dk) {
                    bf16x8 ka = *(const bf16x8*)(kbp + ((row * 128 + dk * 32 + hi * 16) ^ sw));
                    z = MFMA32(ka, qa[dk], z);
                }
                sc[st] = z;
            }
            __builtin_amdgcn_s_setprio(0);
            if (kt * 64 + 63 > q0) {
                const int qg = q0 + ln31;
                const int kbase = kt * 64 + 4 * hi;
#pragma unroll
                for (int st = 0; st < 2; ++st)
#pragma unroll
                    for (int r = 0; r < 16; ++r) {
                        int kg = kbase + st * 32 + (r & 3) + 8 * (r >> 2);
                        if (kg > qg) sc[st][r] = -3.0e38f;
                    }
            }
            float mx = sc[0][0];
#pragma unroll
            for (int r = 1; r < 16; ++r) mx = fmaxf(mx, sc[0][r]);
#pragma unroll
            for (int r = 0; r < 16; ++r) mx = fmaxf(mx, sc[1][r]);
            mx = fmaxf(mx, __shfl_xor(mx, 32));
            float pmax2 = mx * CL2;
            if (__ballot(pmax2 > m2 + 8.0f)) {
                float mnew = fmaxf(m2, pmax2);
                float sf = __builtin_amdgcn_exp2f(m2 - mnew);
                m2 = mnew;
                l *= sf;
#pragma unroll
                for (int r = 0; r < 16; ++r) {
                    float sfr = __shfl(sf, (r & 3) + 8 * (r >> 2) + 4 * hi);
                    acc[0][r] *= sfr;
                    acc[1][r] *= sfr;
                }
            }
            bf16x4 vl[4][2], vh[4][2];
            const unsigned vbase = lds_addr(vbp) + hi * 1024 + ch * 128 + c16 * 8;
#pragma unroll
            for (int ksg = 0; ksg < 4; ++ksg)
#pragma unroll
                for (int dt = 0; dt < 2; ++dt) {
                    asm volatile("ds_read_b64_tr_b16 %0, %2\n\t"
                                 "ds_read_b64_tr_b16 %1, %2 offset:512"
                                 : "=v"(vl[ksg][dt]), "=v"(vh[ksg][dt])
                                 : "v"(vbase + (unsigned)(ksg * 2048 + dt * 256)) : "memory");
                }
            const float mt = m2;
            float sum = 0.f;
            unsigned w[2][8];
#pragma unroll
            for (int st = 0; st < 2; ++st)
#pragma unroll
                for (int n = 0; n < 8; ++n) {
                    float e0 = __builtin_amdgcn_exp2f(fmaf(sc[st][2 * n],     CL2, -mt));
                    float e1 = __builtin_amdgcn_exp2f(fmaf(sc[st][2 * n + 1], CL2, -mt));
                    sum += e0 + e1;
                    w[st][n] = pack2bf(e0, e1);
                }
            sum += __shfl_xor(sum, 32);
            l += sum;
            union { unsigned u[4]; bf16x8 v; } pa[4];
#pragma unroll
            for (int ksg = 0; ksg < 4; ++ksg) {
                const int st = ksg >> 1, kl = ksg & 1;
                unsigned x0 = w[st][4 * kl],     y0 = w[st][4 * kl + 2];
                unsigned x1 = w[st][4 * kl + 1], y1 = w[st][4 * kl + 3];
                asm volatile("v_permlane32_swap_b32 %0, %1" : "+v"(x0), "+v"(y0));
                asm volatile("v_permlane32_swap_b32 %0, %1" : "+v"(x1), "+v"(y1));
                pa[ksg].u[0] = x0; pa[ksg].u[1] = x1; pa[ksg].u[2] = y0; pa[ksg].u[3] = y1;
            }
            asm volatile("s_waitcnt lgkmcnt(0)" ::: "memory");
            __builtin_amdgcn_sched_barrier(0);
            __builtin_amdgcn_s_setprio(1);
#pragma unroll
            for (int ksg = 0; ksg < 4; ++ksg)
#pragma unroll
                for (int dt = 0; dt < 2; ++dt) {
                    bf16x8 vb = __builtin_shufflevector(vl[ksg][dt], vh[ksg][dt],
                                                        0, 1, 2, 3, 4, 5, 6, 7);
                    acc[dt] = MFMA32(pa[ksg].v, vb, acc[dt]);
                }
            __builtin_amdgcn_s_setprio(0);
        }

        // end of iter: drain kt+1's loads (issued one full iter ago -> free),
        // keep kt+2's in flight; barrier publishes them + frees buf cur.
        if (pf) asm volatile("s_waitcnt vmcnt(4)" ::: "memory");
        else    asm volatile("s_waitcnt vmcnt(0)" ::: "memory");
        asm volatile("s_barrier" ::: "memory");
        cur = (cur == 2) ? 0 : cur + 1;
    }

    float invl = 1.f / l;
#pragma unroll
    for (int r = 0; r < 16; ++r) {
        float ir = __shfl(invl, (r & 3) + 8 * (r >> 2) + 4 * hi);
        long orow = rowbase + q0 + (r & 3) + 8 * (r >> 2) + 4 * hi;
#pragma unroll
        for (int dt = 0; dt < 2; ++dt)
            out[orow * Dd + h * HD + dt * 32 + ln31] = __float2bfloat16(acc[dt][r] * ir);
    }
}

extern "C" void kernel_launch(void* const* d_in, const int* in_sizes, int n_in,
                              void* d_out, int out_size, void* d_ws, size_t ws_size,
                              hipStream_t stream) {
    const float* x    = (const float*)d_in[0];
    const float* Wqkv = (const float*)d_in[1];
    const float* Wo_w = (const float*)d_in[2];
    const float* Wo_b = (const float*)d_in[3];
    float* out = (float*)d_out;

    const size_t MB = 1ull << 20;
    char* ws = (char*)d_ws;
    bf16* xb    = (bf16*)(ws);               // 16 MB; reused as attn output
    bf16* wqkvb = (bf16*)(ws + 16 * MB);     // 6 MB
    bf16* wob   = (bf16*)(ws + 22 * MB);     // 2 MB
    bf16* qkv   = (bf16*)(ws + 24 * MB);     // 48 MB
    bf16* attnb = xb;

    cast_all<<<12288, 256, 0, stream>>>(x, Wqkv, Wo_w, xb, wqkvb, wob);

    // qkv = x @ Wqkv^T : 128^2 tiles, grid 24*64 = 1536
    gemm_bt<true><<<dim3(TD / 128, Mrows / 128), 256, 0, stream>>>(
        xb, wqkvb, qkv, nullptr, nullptr, Mrows, TD, Dd);

    attn_fwd7<<<dim3(Bb * Hh, 16), 256, 0, stream>>>(qkv, attnb);

    // out = attn @ Wo^T + b : grid 8*64 = 512
    gemm_bt<false><<<dim3(Dd / 128, Mrows / 128), 256, 0, stream>>>(
        attnb, wob, nullptr, out, Wo_b, Mrows, Dd, Dd);
}

// Round 16
// 144.144 us; speedup vs baseline: 1.1645x; 1.0145x over previous
//
#include <hip/hip_runtime.h>
#include <hip/hip_bf16.h>

using bf16 = __hip_bfloat16;
typedef __attribute__((ext_vector_type(8))) short bf16x8;
typedef __attribute__((ext_vector_type(4))) short bf16x4;
typedef __attribute__((ext_vector_type(4))) float f32x4;
typedef __attribute__((ext_vector_type(16))) float f32x16;

static constexpr int Bb = 4, Ss = 2048, Dd = 1024, Hh = 16, HD = 64;
static constexpr int TD = 3 * Dd;            // 3072
static constexpr int Mrows = Bb * Ss;        // 8192

#define MFMA16(a, b, c) __builtin_amdgcn_mfma_f32_16x16x32_bf16((a), (b), (c), 0, 0, 0)
#define MFMA32(a, b, c) __builtin_amdgcn_mfma_f32_32x32x16_bf16((a), (b), (c), 0, 0, 0)

__device__ __forceinline__ void gload_lds16(const void* g, void* l) {
    __builtin_amdgcn_global_load_lds(
        (const __attribute__((address_space(1))) void*)g,
        (__attribute__((address_space(3))) void*)l, 16, 0, 0);
}

__device__ __forceinline__ unsigned lds_addr(const void* p) {
    return (unsigned)(unsigned long long)(const __attribute__((address_space(3))) char*)p;
}

__device__ __forceinline__ unsigned pack2bf(float a, float b) {
    bf16 x = __float2bfloat16(a), y = __float2bfloat16(b);
    return (unsigned)(*(unsigned short*)&x) | ((unsigned)(*(unsigned short*)&y) << 16);
}

// ---------------- fused cast fp32 -> bf16 (x, Wqkv, Wo in one launch) ------
__global__ void cast_all(const float* __restrict__ x, const float* __restrict__ w1,
                         const float* __restrict__ w2, bf16* __restrict__ xb,
                         bf16* __restrict__ w1b, bf16* __restrict__ w2b) {
    int i = blockIdx.x * blockDim.x + threadIdx.x;   // 4-elem groups
    const float* src; bf16* dst; int off;
    if (i < 2097152)      { src = x;  dst = xb;  off = i; }
    else if (i < 2883584) { src = w1; dst = w1b; off = i - 2097152; }
    else                  { src = w2; dst = w2b; off = i - 2883584; }
    float4 v = ((const float4*)src)[off];
    uint2 o;
    o.x = pack2bf(v.x, v.y);
    o.y = pack2bf(v.z, v.w);
    *(uint2*)(dst + 4l * off) = o;
}

// ---------------- GEMM: C[m,n] = sum_k A[m,k] * Bt[n,k] ----------------
// r14 proven win: 128x128 tile, BK=64, XOR-swizzled LDS (128B rows),
// simple 2-barrier loop, 32KB LDS, (256,4). Conflicts 6.3M -> ~0. UNCHANGED.
template<bool OUT_BF16>
__global__ __launch_bounds__(256, 4) void gemm_bt(
    const bf16* __restrict__ A, const bf16* __restrict__ Bt,
    bf16* __restrict__ Cb, float* __restrict__ Cf, const float* __restrict__ bias,
    int M, int N, int K)
{
    __shared__ __align__(16) bf16 As[128 * 64];   // 16 KB
    __shared__ __align__(16) bf16 Bs[128 * 64];   // 16 KB
    const int tid = threadIdx.x;
    const int lane = tid & 63, wid = tid >> 6;
    const int lc = lane & 15, lg = lane >> 4;
    const int wr = wid >> 1, wc = wid & 1;

    const int nwg = gridDim.x * gridDim.y;
    int orig = blockIdx.y * gridDim.x + blockIdx.x;
    int swz = orig;
    if ((nwg & 7) == 0) swz = (orig & 7) * (nwg >> 3) + (orig >> 3);
    const long tile_m = (long)(swz / (int)gridDim.x) * 128;
    const long tile_n = (long)(swz % (int)gridDim.x) * 128;

    const f32x4 fz = {0.f, 0.f, 0.f, 0.f};
    f32x4 acc[4][4];
#pragma unroll
    for (int i = 0; i < 4; ++i)
#pragma unroll
        for (int j = 0; j < 4; ++j) acc[i][j] = fz;

    for (int k0 = 0; k0 < K; k0 += 64) {
#pragma unroll
        for (int it = 0; it < 4; ++it) {
            int s = tid + it * 256;
            int r = s >> 3;
            int cs = (s & 7) ^ (r & 7);
            gload_lds16(A  + (tile_m + r) * (long)K + k0 + cs * 8, (char*)As + s * 16);
            gload_lds16(Bt + (tile_n + r) * (long)K + k0 + cs * 8, (char*)Bs + s * 16);
        }
        __syncthreads();
#pragma unroll
        for (int ks = 0; ks < 2; ++ks) {
            bf16x8 af[4], bfr[4];
#pragma unroll
            for (int i = 0; i < 4; ++i) {
                int rowa = wr * 64 + i * 16 + lc;
                af[i] = *(const bf16x8*)((const char*)As +
                        ((rowa * 128 + ks * 64 + lg * 16) ^ ((rowa & 7) << 4)));
                int rowb = wc * 64 + i * 16 + lc;
                bfr[i] = *(const bf16x8*)((const char*)Bs +
                        ((rowb * 128 + ks * 64 + lg * 16) ^ ((rowb & 7) << 4)));
            }
#pragma unroll
            for (int i = 0; i < 4; ++i)
#pragma unroll
                for (int j = 0; j < 4; ++j)
                    acc[i][j] = MFMA16(af[i], bfr[j], acc[i][j]);
        }
        __syncthreads();
    }
#pragma unroll
    for (int i = 0; i < 4; ++i)
#pragma unroll
        for (int j = 0; j < 4; ++j)
#pragma unroll
            for (int r = 0; r < 4; ++r) {
                long row = tile_m + wr * 64 + i * 16 + lg * 4 + r;
                long col = tile_n + wc * 64 + j * 16 + lc;
                float v = acc[i][j][r];
                if constexpr (OUT_BF16) Cb[row * N + col] = __float2bfloat16(v);
                else                    Cf[row * N + col] = v + bias[col];
            }
}

// ---------------- causal flash attention v8: v6 + VALU diet ----------------
// v6 structure (2-buffer, heavy-first, single strip) with the softmax VALU
// cost cut: (1) P->bf16 via v_cvt_pk_bf16_f32 inline asm (1 inst/pair vs
// ~10 for software-RNE __float2bfloat16 pair) [T12]; (2) depth-5 tree
// row-max (was depth-31 chain); (3) 4-way partial sums (was depth-32
// chain); (4) tr-read offsets as literal immediates (saves 8 v_add/tile).
__global__ __launch_bounds__(256, 2) void attn_fwd8(const bf16* __restrict__ qkv,
                                                    bf16* __restrict__ out) {
    const int bh = blockIdx.x;                 // 0..63
    const int p  = blockIdx.y;                 // 0..15
    const int s  = 15 - p;                     // strip index, heavy first
    const int b = bh >> 4, h = bh & 15;
    const int tid = threadIdx.x;
    const int lane = tid & 63, wid = tid >> 6;
    const int ln31 = lane & 31, hi = lane >> 5;
    const int ch = (lane >> 4) & 1, c16 = lane & 15;
    const long rowbase = (long)b * Ss;
    const int q0 = s * 128 + wid * 32;         // this wave's 32 q-rows
    const int nt = 2 * s + 2;                  // causal kv tiles
    const float CL2 = 0.18033688f;             // 0.125 * log2(e)

    __shared__ __align__(16) bf16 Ks[2][64 * 64];
    __shared__ __align__(16) bf16 Vs[2][64 * 64];

    const int sK0 = tid, sK1 = tid + 256;
    const int rK0 = sK0 >> 3, cK0 = ((sK0 & 7) ^ (rK0 & 7)) * 8;
    const int rK1 = sK1 >> 3, cK1 = ((sK1 & 7) ^ (rK1 & 7)) * 8;
    const int rV0 = ((sK0 >> 5) << 2) | ((sK0 >> 1) & 3);
    const int cV0 = ((((sK0 >> 3) & 3) << 1) | (sK0 & 1)) * 8;
    const int rV1 = ((sK1 >> 5) << 2) | ((sK1 >> 1) & 3);
    const int cV1 = ((((sK1 >> 3) & 3) << 1) | (sK1 & 1)) * 8;
    const bf16* gK0 = qkv + (rowbase + rK0) * (long)TD + h * HD + Dd + cK0;
    const bf16* gK1 = qkv + (rowbase + rK1) * (long)TD + h * HD + Dd + cK1;
    const bf16* gV0 = qkv + (rowbase + rV0) * (long)TD + h * HD + 2 * Dd + cV0;
    const bf16* gV1 = qkv + (rowbase + rV1) * (long)TD + h * HD + 2 * Dd + cV1;

    auto STAGE = [&](int buf, int kt) {
        const long o = (long)kt * 64 * TD;
        gload_lds16(gK0 + o, (char*)Ks[buf] + tid * 16);
        gload_lds16(gK1 + o, (char*)Ks[buf] + 4096 + tid * 16);
        gload_lds16(gV0 + o, (char*)Vs[buf] + tid * 16);
        gload_lds16(gV1 + o, (char*)Vs[buf] + 4096 + tid * 16);
    };

    bf16x8 qa[4];
#pragma unroll
    for (int dk = 0; dk < 4; ++dk)
        qa[dk] = *(const bf16x8*)(qkv + (rowbase + q0 + ln31) * (long)TD + h * HD + dk * 16 + hi * 8);

    f32x16 acc[2];
#pragma unroll
    for (int dt = 0; dt < 2; ++dt) acc[dt] = (f32x16)0.0f;
    float m2 = -3.0e38f;
    float l = 0.f;

    STAGE(0, 0);
    __syncthreads();

    for (int kt = 0; kt < nt; ++kt) {
        const int cur = kt & 1;
        if (kt + 1 < nt) STAGE(cur ^ 1, kt + 1);

        if (kt * 64 <= q0 + 31) {
            const char* kbp = (const char*)Ks[cur];
            const char* vbp = (const char*)Vs[cur];
            f32x16 sc[2];
            __builtin_amdgcn_s_setprio(1);
#pragma unroll
            for (int st = 0; st < 2; ++st) {
                f32x16 z = (f32x16)0.0f;
                const int row = st * 32 + ln31;
                const int sw = (row & 7) << 4;
#pragma unroll
                for (int dk = 0; dk < 4; ++dk) {
                    bf16x8 ka = *(const bf16x8*)(kbp + ((row * 128 + dk * 32 + hi * 16) ^ sw));
                    z = MFMA32(ka, qa[dk], z);
                }
                sc[st] = z;
            }
            __builtin_amdgcn_s_setprio(0);
            if (kt * 64 + 63 > q0) {
                const int qg = q0 + ln31;
                const int kbase = kt * 64 + 4 * hi;
#pragma unroll
                for (int st = 0; st < 2; ++st)
#pragma unroll
                    for (int r = 0; r < 16; ++r) {
                        int kg = kbase + st * 32 + (r & 3) + 8 * (r >> 2);
                        if (kg > qg) sc[st][r] = -3.0e38f;
                    }
            }
            // ---- row max: depth-5 pairwise tree (was depth-31 chain) ----
            float mt16[16];
#pragma unroll
            for (int r = 0; r < 16; ++r) mt16[r] = fmaxf(sc[0][r], sc[1][r]);
#pragma unroll
            for (int off = 8; off; off >>= 1)
#pragma unroll
                for (int r = 0; r < off; ++r) mt16[r] = fmaxf(mt16[r], mt16[r + off]);
            float mx = fmaxf(mt16[0], __shfl_xor(mt16[0], 32));
            float pmax2 = mx * CL2;
            // ---- defer-max rescale (rare) ----
            if (__ballot(pmax2 > m2 + 8.0f)) {
                float mnew = fmaxf(m2, pmax2);
                float sf = __builtin_amdgcn_exp2f(m2 - mnew);
                m2 = mnew;
                l *= sf;
#pragma unroll
                for (int r = 0; r < 16; ++r) {
                    float sfr = __shfl(sf, (r & 3) + 8 * (r >> 2) + 4 * hi);
                    acc[0][r] *= sfr;
                    acc[1][r] *= sfr;
                }
            }
            // ---- issue all 16 V tr-reads early (literal offsets, 1 base) ----
            bf16x4 vl[4][2], vh[4][2];
            const unsigned vbase = lds_addr(vbp) + hi * 1024 + ch * 128 + c16 * 8;
#define TRRD(L, H, O1, O2) \
            asm volatile("ds_read_b64_tr_b16 %0, %2 offset:" O1 "\n\t" \
                         "ds_read_b64_tr_b16 %1, %2 offset:" O2 \
                         : "=v"(L), "=v"(H) : "v"(vbase) : "memory");
            TRRD(vl[0][0], vh[0][0], "0",    "512")
            TRRD(vl[0][1], vh[0][1], "256",  "768")
            TRRD(vl[1][0], vh[1][0], "2048", "2560")
            TRRD(vl[1][1], vh[1][1], "2304", "2816")
            TRRD(vl[2][0], vh[2][0], "4096", "4608")
            TRRD(vl[2][1], vh[2][1], "4352", "4864")
            TRRD(vl[3][0], vh[3][0], "6144", "6656")
            TRRD(vl[3][1], vh[3][1], "6400", "6912")
#undef TRRD
            // ---- exp + 4-way partial sums + hw cvt_pk pack ----
            const float mt = m2;
            float s4[4] = {0.f, 0.f, 0.f, 0.f};
            unsigned w[2][8];
#pragma unroll
            for (int st = 0; st < 2; ++st)
#pragma unroll
                for (int n = 0; n < 8; ++n) {
                    float e0 = __builtin_amdgcn_exp2f(fmaf(sc[st][2 * n],     CL2, -mt));
                    float e1 = __builtin_amdgcn_exp2f(fmaf(sc[st][2 * n + 1], CL2, -mt));
                    s4[n & 3] += e0 + e1;
                    asm("v_cvt_pk_bf16_f32 %0, %1, %2"
                        : "=v"(w[st][n]) : "v"(e0), "v"(e1));
                }
            float sum = (s4[0] + s4[1]) + (s4[2] + s4[3]);
            sum += __shfl_xor(sum, 32);
            l += sum;
            // ---- P exchange: 8 permlane32_swap ----
            union { unsigned u[4]; bf16x8 v; } pa[4];
#pragma unroll
            for (int ksg = 0; ksg < 4; ++ksg) {
                const int st = ksg >> 1, kl = ksg & 1;
                unsigned x0 = w[st][4 * kl],     y0 = w[st][4 * kl + 2];
                unsigned x1 = w[st][4 * kl + 1], y1 = w[st][4 * kl + 3];
                asm volatile("v_permlane32_swap_b32 %0, %1" : "+v"(x0), "+v"(y0));
                asm volatile("v_permlane32_swap_b32 %0, %1" : "+v"(x1), "+v"(y1));
                pa[ksg].u[0] = x0; pa[ksg].u[1] = x1; pa[ksg].u[2] = y0; pa[ksg].u[3] = y1;
            }
            // ---- PV ----
            asm volatile("s_waitcnt lgkmcnt(0)" ::: "memory");
            __builtin_amdgcn_sched_barrier(0);
            __builtin_amdgcn_s_setprio(1);
#pragma unroll
            for (int ksg = 0; ksg < 4; ++ksg)
#pragma unroll
                for (int dt = 0; dt < 2; ++dt) {
                    bf16x8 vb = __builtin_shufflevector(vl[ksg][dt], vh[ksg][dt],
                                                        0, 1, 2, 3, 4, 5, 6, 7);
                    acc[dt] = MFMA32(pa[ksg].v, vb, acc[dt]);
                }
            __builtin_amdgcn_s_setprio(0);
        }

        __syncthreads();
    }

    float invl = 1.f / l;
#pragma unroll
    for (int r = 0; r < 16; ++r) {
        float ir = __shfl(invl, (r & 3) + 8 * (r >> 2) + 4 * hi);
        long orow = rowbase + q0 + (r & 3) + 8 * (r >> 2) + 4 * hi;
#pragma unroll
        for (int dt = 0; dt < 2; ++dt)
            out[orow * Dd + h * HD + dt * 32 + ln31] = __float2bfloat16(acc[dt][r] * ir);
    }
}

extern "C" void kernel_launch(void* const* d_in, const int* in_sizes, int n_in,
                              void* d_out, int out_size, void* d_ws, size_t ws_size,
                              hipStream_t stream) {
    const float* x    = (const float*)d_in[0];
    const float* Wqkv = (const float*)d_in[1];
    const float* Wo_w = (const float*)d_in[2];
    const float* Wo_b = (const float*)d_in[3];
    float* out = (float*)d_out;

    const size_t MB = 1ull << 20;
    char* ws = (char*)d_ws;
    bf16* xb    = (bf16*)(ws);               // 16 MB; reused as attn output
    bf16* wqkvb = (bf16*)(ws + 16 * MB);     // 6 MB
    bf16* wob   = (bf16*)(ws + 22 * MB);     // 2 MB
    bf16* qkv   = (bf16*)(ws + 24 * MB);     // 48 MB
    bf16* attnb = xb;

    cast_all<<<12288, 256, 0, stream>>>(x, Wqkv, Wo_w, xb, wqkvb, wob);

    // qkv = x @ Wqkv^T : 128^2 tiles, grid 24*64 = 1536
    gemm_bt<true><<<dim3(TD / 128, Mrows / 128), 256, 0, stream>>>(
        xb, wqkvb, qkv, nullptr, nullptr, Mrows, TD, Dd);

    attn_fwd8<<<dim3(Bb * Hh, 16), 256, 0, stream>>>(qkv, attnb);

    // out = attn @ Wo^T + b : grid 8*64 = 512
    gemm_bt<false><<<dim3(Dd / 128, Mrows / 128), 256, 0, stream>>>(
        attnb, wob, nullptr, out, Wo_b, Mrows, Dd, Dd);
}